// Round 12
// baseline (434.556 us; speedup 1.0000x reference)
//
#include <hip/hip_runtime.h>
#include <hip/hip_cooperative_groups.h>
#include <math.h>

namespace cg = cooperative_groups;

#define M_CELLS 3872
#define M_PAD   3968   // 31 * 128
#define NPIX    16384  // 128*128

typedef _Float16 half8 __attribute__((ext_vector_type(8)));
typedef float f32x4 __attribute__((ext_vector_type(4)));

// async global->LDS 16B: per-lane global addr, wave-uniform LDS base (+lane*16 in HW)
#define GL2LDS(g, l) __builtin_amdgcn_global_load_lds( \
    (const __attribute__((address_space(1))) unsigned int*)(g), \
    (__attribute__((address_space(3))) unsigned int*)(l), 16, 0, 0)

// ===================== workspace layouts =====================
static constexpr size_t ALN(size_t x){ return (x + 255) & ~(size_t)255; }

// ---- fallback layout ----
static constexpr size_t F_KF   = 0;
static constexpr size_t F_SC   = F_KF + (size_t)M_CELLS*128*4;
static constexpr size_t F_SM   = F_SC + (size_t)M_CELLS*4;
static constexpr size_t F_CS   = F_SM + (size_t)M_CELLS*4;
static constexpr size_t F_BIT  = F_CS + (size_t)M_CELLS*4;
static constexpr size_t F_SPP  = F_BIT + (size_t)M_CELLS*256*8;
static constexpr size_t F_TIDX = F_SPP + (size_t)64*M_CELLS*4;
static constexpr size_t F_TSC  = F_TIDX + 512*4;
static constexpr size_t F_SMT  = F_TSC + 512*4;
static constexpr size_t F_IOU  = F_SMT + 512*4;
static constexpr size_t F_COMP = F_IOU + (size_t)500*500*4;
static constexpr size_t F_NMS  = F_COMP + 512*4;
static constexpr size_t F_SEL  = F_NMS + 512*4;
static constexpr size_t F_SELP = F_SEL + 32*4;
static constexpr size_t F_RMN  = ALN(F_SELP + (size_t)30*NPIX*4);   // int[30*512] per-row min-x
static constexpr size_t F_RMX  = F_RMN + 30*512*4;                  // int[30*512] per-row max-x
static constexpr size_t F_KEYS = ALN(F_RMX + 30*512*4);
static constexpr size_t WS_FB  = F_KEYS + 4096*8;

// ---- MFMA layout (~25 MB, proven to fit in rounds 2-11) ----
static constexpr size_t B_KF   = 0;                                       // float kfT[128][M_PAD] e-major
static constexpr size_t B_AFR  = ALN(B_KF  + (size_t)M_PAD*128*4);        // frag A: [31][8 sub][512 pc][16B] = 2MB
static constexpr size_t B_BFR  = ALN(B_AFR + (size_t)31*4096*16);         // frag B: [128][8 sub][512 pc][16B] = 8MB
static constexpr size_t B_SC   = ALN(B_BFR + (size_t)128*4096*16);
static constexpr size_t B_SM   = ALN(B_SC + (size_t)M_PAD*4);
static constexpr size_t B_CS   = ALN(B_SM + (size_t)M_PAD*4);
static constexpr size_t B_BIT  = ALN(B_CS + (size_t)M_PAD*4);
static constexpr size_t B_SPP  = ALN(B_BIT + (size_t)M_PAD*256*8);
static constexpr size_t B_TIDX = ALN(B_SPP + (size_t)128*M_PAD*4);
static constexpr size_t B_TSC  = ALN(B_TIDX + 512*4);
static constexpr size_t B_SMT  = ALN(B_TSC + 512*4);
static constexpr size_t B_IOU  = ALN(B_SMT + 512*4);
static constexpr size_t B_COMP = ALN(B_IOU + (size_t)500*500*4);
static constexpr size_t B_NMS  = ALN(B_COMP + 512*4);
static constexpr size_t B_SEL  = ALN(B_NMS + 512*4);
static constexpr size_t B_SELP = ALN(B_SEL + 32*4);
static constexpr size_t B_RMN  = ALN(B_SELP + (size_t)30*NPIX*4);
static constexpr size_t B_RMX  = B_RMN + 30*512*4;
static constexpr size_t B_CMAP = ALN(B_RMX + 30*512*4);   // int[4096] newIdx -> cell
static constexpr size_t B_RMAP = B_CMAP + 4096*4;         // int[4096] cell -> newIdx | -1
static constexpr size_t B_VCNT = B_RMAP + 4096*4;         // int[64]
static constexpr size_t B_KEYS = ALN(B_VCNT + 64*4);      // u64[4096]
static constexpr size_t B_AF30 = ALN(B_KEYS + 4096*8);    // frag A30: [8 sub][128 pc][16B] = 16KB
static constexpr size_t WS_MFMA = B_AF30 + 8*128*16;

__device__ inline unsigned long long packkey(float v, int i) {
  return ((unsigned long long)__float_as_uint(v) << 32) | (unsigned)(0xFFFFFFFFu - (unsigned)i);
}

// ===================== K0aT (MFMA): gather kernels e-major + scores + inline compaction =====================
__global__ __launch_bounds__(256) void k0aT_gather(
    const float* __restrict__ c0,const float* __restrict__ c1,const float* __restrict__ c2,
    const float* __restrict__ c3,const float* __restrict__ c4,
    const float* __restrict__ w0,const float* __restrict__ w1,const float* __restrict__ w2,
    const float* __restrict__ w3,const float* __restrict__ w4,
    float* __restrict__ kfT, float* __restrict__ scores,
    int* __restrict__ cmap, int* __restrict__ rmap, int* __restrict__ vcnt) {
  const int lvl = blockIdx.y;
  const int Gs[5]   = {1600,1296,576,256,144};
  const int offs[5] = {0,1600,2896,3472,3728};
  const int G = Gs[lvl], off = offs[lvl];
  const float* kl = (lvl==0)?w0:(lvl==1)?w1:(lvl==2)?w2:(lvl==3)?w3:w4;
  const float* cl = (lvl==0)?c0:(lvl==1)?c1:(lvl==2)?c2:(lvl==3)?c3:c4;
  int t = blockIdx.x*256 + threadIdx.x;
  if (t >= G*128) return;
  int e = t / G, c = t - e*G;
  kfT[(size_t)e*M_PAD + off + c] = kl[t];
  if (e == 0) {
    int cell = off + c;
    float sc = cl[c];
    scores[cell] = sc;
    if (sc > 0.3f) {
      int run = atomicAdd(vcnt, 1);
      cmap[run] = cell;
      rmap[cell] = run;
    } else rmap[cell] = -1;
  }
}

// ===================== K0a (fallback): row-major kf =====================
__global__ __launch_bounds__(256) void k0a_gather(
    const float* __restrict__ c0,const float* __restrict__ c1,const float* __restrict__ c2,
    const float* __restrict__ c3,const float* __restrict__ c4,
    const float* __restrict__ w0,const float* __restrict__ w1,const float* __restrict__ w2,
    const float* __restrict__ w3,const float* __restrict__ w4,
    float* __restrict__ kf, float* __restrict__ scores) {
  const int lvl = blockIdx.y;
  const int Gs[5]   = {1600,1296,576,256,144};
  const int offs[5] = {0,1600,2896,3472,3728};
  const int G = Gs[lvl], off = offs[lvl];
  const float* kl = (lvl==0)?w0:(lvl==1)?w1:(lvl==2)?w2:(lvl==3)?w3:w4;
  const float* cl = (lvl==0)?c0:(lvl==1)?c1:(lvl==2)?c2:(lvl==3)?c3:c4;
  int t = blockIdx.x*256 + threadIdx.x;
  if (t >= G*128) return;
  int e = t / G, c = t - e*G;
  kf[(size_t)(off+c)*128 + e] = kl[t];
  if (e == 0) scores[off+c] = cl[c];
}

// ===================== K0b: kfT -> frag-ordered A (compacted rows) =====================
__global__ __launch_bounds__(256) void k0b_afrag(const float* __restrict__ kfT,
                                                 const int* __restrict__ cmap,
                                                 const int* __restrict__ vcnt,
                                                 _Float16* __restrict__ Af) {
  int P = blockIdx.x*256 + threadIdx.x;     // 31*4096 = 126976
  int mblock = P >> 12;
  int r  = P & 4095;
  int sub = r >> 9, pc = r & 511;
  int ks = sub >> 1, h = sub & 1;
  int mn = pc >> 6, ln = pc & 63;
  int mcomp = mblock*128 + mn*16 + (ln & 15);
  int kb = ks*32 + (ln >> 4)*8;
  half8 o;
  if (mcomp < vcnt[0]) {
    const float* src = kfT + cmap[mcomp];
    #pragma unroll
    for (int j=0;j<8;j++) {
      float x = src[(size_t)(kb+j)*M_PAD];
      _Float16 hi = (_Float16)x;
      o[j] = h ? (_Float16)(x - (float)hi) : hi;
    }
  } else {
    #pragma unroll
    for (int j=0;j<8;j++) o[j] = (_Float16)0.f;
  }
  *(half8*)&Af[(size_t)P*8] = o;
}

// ===================== K0c: seg -> frag-ordered B =====================
__global__ __launch_bounds__(256) void k0c_bfrag(const float* __restrict__ seg,
                                                 _Float16* __restrict__ Bf) {
  int P = blockIdx.x*256 + threadIdx.x;     // 128*4096 = 524288
  int nb = P >> 12;
  int r  = P & 4095;
  int sub = r >> 9, pc = r & 511;
  int ks = sub >> 1, h = sub & 1;
  int mn = pc >> 6, ln = pc & 63;
  int px = nb*128 + mn*16 + (ln & 15);
  int kb = ks*32 + (ln >> 4)*8;
  half8 o;
  #pragma unroll
  for (int j=0;j<8;j++) {
    float x = seg[(size_t)(kb+j)*NPIX + px];
    _Float16 hi = (_Float16)x;
    o[j] = h ? (_Float16)(x - (float)hi) : hi;
  }
  *(half8*)&Bf[(size_t)P*8] = o;
}

// ===================== K1 (fallback): fp32 vector GEMM =====================
__global__ __launch_bounds__(256, 6) void k1_gemm(
    const float* __restrict__ kf, const float* __restrict__ seg,
    unsigned long long* __restrict__ bits, float* __restrict__ spp) {
  int tid = threadIdx.x;
  int p  = blockIdx.x*256 + tid;
  int c0 = blockIdx.y*32;
  float acc[32];
  #pragma unroll
  for (int c=0;c<32;c++) acc[c]=0.f;
  for (int ch=0; ch<8; ch++) {
    float s[16];
    #pragma unroll
    for (int e=0;e<16;e++) s[e] = seg[(size_t)(ch*16+e)*NPIX + p];
    #pragma unroll
    for (int c=0;c<32;c++) {
      float a=0.f;
      #pragma unroll
      for (int e=0;e<16;e++) a = fmaf(kf[(size_t)(c0+c)*128 + ch*16 + e], s[e], a);
      acc[c] += a;
    }
  }
  int wv = tid>>6, ln = tid&63;
  __shared__ float wsum[32][4];
  #pragma unroll
  for (int c=0;c<32;c++) {
    float logit = acc[c];
    bool msk = logit > 0.f;
    unsigned long long bal = __ballot(msk);
    float pr = msk ? __fdividef(1.f, 1.f + __expf(-logit)) : 0.f;
    #pragma unroll
    for (int o=32;o>0;o>>=1) pr += __shfl_down(pr, o);
    if (ln==0) {
      bits[(size_t)(c0+c)*256 + blockIdx.x*4 + wv] = bal;
      wsum[c][wv] = pr;
    }
  }
  __syncthreads();
  if (tid < 32)
    spp[(size_t)blockIdx.x*M_CELLS + c0 + tid] = wsum[tid][0]+wsum[tid][1]+wsum[tid][2]+wsum[tid][3];
}

// ===================== K1 (MFMA): compacted rows; 16KB sub-steps, dbuf, (256,4) =====================
// NOTE: (256,5) forced VGPR 64->48 and spilled acc to scratch (431MB HBM writes, 2.2x slower).
// (256,4) keeps VGPR=64, no spill — measured 60 µs. Do not raise min-waves here.
__global__ __launch_bounds__(256, 4) void k1_mfma(
    const _Float16* __restrict__ Af, const _Float16* __restrict__ Bf,
    const int* __restrict__ vcnt,
    unsigned long long* __restrict__ bits, float* __restrict__ spp) {
  if (blockIdx.x*128 >= vcnt[0]) return;   // compacted tail: no valid rows
  __shared__ char lds[32768];   // 2 x (A 8KB | B 8KB)
  const int tid  = threadIdx.x;
  const int lane = tid & 63;
  const int wave = tid >> 6;
  const int wr = wave >> 1, wc = wave & 1;
  const char* gA = (const char*)Af + (size_t)blockIdx.x*65536;
  const char* gB = (const char*)Bf + (size_t)blockIdx.y*65536;

  f32x4 acc[4][4];
  #pragma unroll
  for (int a=0;a<4;a++)
    #pragma unroll
    for (int b=0;b<4;b++) acc[a][b] = (f32x4){0.f,0.f,0.f,0.f};

  auto issue = [&](int sub, int buf) {
    const char* ga = gA + sub*8192;
    const char* gb = gB + sub*8192;
    char* la = &lds[buf*16384];
    char* lb = &lds[buf*16384 + 8192];
    GL2LDS(ga +  wave   *1024 + lane*16, la +  wave   *1024);
    GL2LDS(ga + (wave+4)*1024 + lane*16, la + (wave+4)*1024);
    GL2LDS(gb +  wave   *1024 + lane*16, lb +  wave   *1024);
    GL2LDS(gb + (wave+4)*1024 + lane*16, lb + (wave+4)*1024);
  };

  issue(0, 0);
  half8 ah[4], bh[4];
  #pragma unroll
  for (int s=0; s<8; s++) {
    __syncthreads();
    if (s < 7) issue(s+1, (s+1)&1);
    const char* lb_ = &lds[(s&1)*16384];
    if ((s & 1) == 0) {
      #pragma unroll
      for (int mt=0; mt<4; mt++) ah[mt] = *(const half8*)&lb_[(wr*4+mt)*1024 + lane*16];
      #pragma unroll
      for (int nt=0; nt<4; nt++) bh[nt] = *(const half8*)&lb_[8192 + (wc*4+nt)*1024 + lane*16];
      #pragma unroll
      for (int nt=0; nt<4; nt++)
        #pragma unroll
        for (int mt=0; mt<4; mt++)
          acc[mt][nt] = __builtin_amdgcn_mfma_f32_16x16x32_f16(ah[mt], bh[nt], acc[mt][nt], 0, 0, 0);
    } else {
      #pragma unroll
      for (int nt=0; nt<4; nt++) {
        half8 bl = *(const half8*)&lb_[8192 + (wc*4+nt)*1024 + lane*16];
        #pragma unroll
        for (int mt=0; mt<4; mt++)
          acc[mt][nt] = __builtin_amdgcn_mfma_f32_16x16x32_f16(ah[mt], bl, acc[mt][nt], 0, 0, 0);
      }
      #pragma unroll
      for (int mt=0; mt<4; mt++) {
        half8 al = *(const half8*)&lb_[(wr*4+mt)*1024 + lane*16];
        #pragma unroll
        for (int nt=0; nt<4; nt++)
          acc[mt][nt] = __builtin_amdgcn_mfma_f32_16x16x32_f16(al, bh[nt], acc[mt][nt], 0, 0, 0);
      }
    }
  }
  __syncthreads();

  const int q = lane >> 4, mm = lane & 15;
  const int mbase = blockIdx.x * 128;
  const int wordIdx = blockIdx.y*2 + wc;
  float* ldsf = (float*)lds;
  #pragma unroll
  for (int mt=0; mt<4; mt++) {
    #pragma unroll
    for (int reg=0; reg<4; reg++) {
      unsigned long long bal[4];
      float ps = 0.f;
      #pragma unroll
      for (int nt=0; nt<4; nt++) {
        float lg = acc[mt][nt][reg];
        bal[nt] = __ballot(lg > 0.f);
        if (lg > 0.f) ps += __fdividef(1.f, 1.f + __expf(-lg));
      }
      ps += __shfl_xor(ps, 1); ps += __shfl_xor(ps, 2);
      ps += __shfl_xor(ps, 4); ps += __shfl_xor(ps, 8);
      if (mm == 0) {
        int cl = wr*64 + mt*16 + q*4 + reg;
        unsigned long long wd = 0;
        #pragma unroll
        for (int nt=0; nt<4; nt++)
          wd |= ((bal[nt] >> (q*16)) & 0xFFFFull) << (nt*16);
        bits[(size_t)(mbase + cl)*256 + wordIdx] = wd;
        ldsf[cl*2 + wc] = ps;
      }
    }
  }
  __syncthreads();
  if (tid < 128)
    spp[(size_t)blockIdx.y*M_PAD + mbase + tid] = ldsf[tid*2] + ldsf[tid*2+1];
}

// ===================== K2 (fallback): original full version =====================
__global__ __launch_bounds__(256) void k2_cscore(
    const unsigned long long* __restrict__ bits, const float* __restrict__ spp,
    const float* __restrict__ scores, float* __restrict__ summ, float* __restrict__ cs,
    int nparts, int mp) {
  int cell = blockIdx.x*4 + (threadIdx.x>>6);
  int ln = threadIdx.x & 63;
  const unsigned long long* row = bits + (size_t)cell*256;
  int cnt = 0;
  #pragma unroll
  for (int k=0;k<4;k++) cnt += __popcll(row[ln + 64*k]);
  float sp = 0.f;
  for (int i=ln; i<nparts; i+=64) sp += spp[(size_t)i*mp + cell];
  #pragma unroll
  for (int o=32;o>0;o>>=1) { cnt += __shfl_down(cnt,o); sp += __shfl_down(sp,o); }
  if (ln==0) {
    float smf = (float)cnt;
    float sc = scores[cell];
    float strd = (cell<1600)?4.f:(cell<2896)?8.f:(cell<3472)?16.f:(cell<3728)?32.f:64.f;
    bool keep = (sc > 0.3f) && (smf > strd);
    float ss = sp / fmaxf(smf, 1.f);
    summ[cell] = smf;
    cs[cell] = keep ? sc*ss : 0.f;
  }
}

// ===================== COOP1: k2c + k3a + k3b fused (grid 242 x 1024) =====================
__global__ __launch_bounds__(1024) void coop_sort(
    const unsigned long long* __restrict__ bits, const float* __restrict__ spp,
    const float* __restrict__ scores, const int* __restrict__ rmap,
    float* __restrict__ summ, float* __restrict__ cs,
    unsigned long long* __restrict__ keys,
    int* __restrict__ tidx, float* __restrict__ tsc, float* __restrict__ smt) {
  cg::grid_group grid = cg::this_grid();
  __shared__ unsigned long long key[4096];
  int tid = threadIdx.x;
  // ---- phase A: cscore (16 cells/block, 242*16 = 3872 exactly) ----
  {
    int cell = blockIdx.x*16 + (tid>>6);
    int ln = tid & 63;
    int ridx = rmap[cell];
    if (ridx < 0) {
      if (ln==0) { summ[cell]=0.f; cs[cell]=0.f; }
    } else {
      const unsigned long long* row = bits + (size_t)ridx*256;
      int cnt = 0;
      #pragma unroll
      for (int k=0;k<4;k++) cnt += __popcll(row[ln + 64*k]);
      float sp = spp[(size_t)ln*M_PAD + ridx] + spp[(size_t)(ln+64)*M_PAD + ridx];
      #pragma unroll
      for (int o=32;o>0;o>>=1) { cnt += __shfl_down(cnt,o); sp += __shfl_down(sp,o); }
      if (ln==0) {
        float smf = (float)cnt;
        float sc = scores[cell];
        float strd = (cell<1600)?4.f:(cell<2896)?8.f:(cell<3472)?16.f:(cell<3728)?32.f:64.f;
        bool keep = (smf > strd);
        float ss = sp / fmaxf(smf, 1.f);
        summ[cell] = smf;
        cs[cell] = keep ? sc*ss : 0.f;
      }
    }
  }
  grid.sync();
  // ---- phase B: bitonic sizes 2..512 on 8 segments (blocks 0..7) ----
  if (blockIdx.x < 8) {
    int b = blockIdx.x;
    if (tid < 512) {
      int gi = b*512 + tid;
      key[tid] = (gi < M_CELLS) ? packkey(cs[gi], gi) : 0ULL;
    }
    __syncthreads();
    for (int size=2; size<=512; size<<=1) {
      for (int st=size>>1; st>0; st>>=1) {
        if (tid < 512) {
          int i = tid, pp = i ^ st;
          if (pp > i) {
            unsigned long long a=key[i], bb=key[pp];
            bool desc = (((b*512+i) & size) == 0);
            if (desc ? (a<bb) : (a>bb)) { key[i]=bb; key[pp]=a; }
          }
        }
        __syncthreads();
      }
    }
    if (tid < 512) keys[b*512+tid] = key[tid];
  }
  grid.sync();
  // ---- phase C: merge sizes 1024..4096 + emit top500 (block 0) ----
  if (blockIdx.x == 0) {
    for (int i=tid;i<4096;i+=1024) key[i] = keys[i];
    __syncthreads();
    for (int size=1024; size<=4096; size<<=1) {
      for (int st=size>>1; st>0; st>>=1) {
        for (int i=tid;i<4096;i+=1024) {
          int pp = i ^ st;
          if (pp > i) {
            unsigned long long a=key[i], b=key[pp];
            bool desc = ((i & size) == 0);
            if (desc ? (a<b) : (a>b)) { key[i]=b; key[pp]=a; }
          }
        }
        __syncthreads();
      }
    }
    if (tid < 512) {
      if (tid < 500) {
        unsigned long long k = key[tid];
        int idx = (int)(0xFFFFFFFFu - (unsigned)(k & 0xFFFFFFFFull));
        tidx[tid] = idx;
        tsc[tid] = __uint_as_float((unsigned)(k>>32));
        smt[tid] = summ[idx];
      } else { tidx[tid]=0; tsc[tid]=0.f; smt[tid]=0.f; }
    }
  }
}

// ===================== K3a/K3b standalone (fallback path) =====================
__global__ __launch_bounds__(256) void k3a_sort512(const float* __restrict__ cs,
                                                   unsigned long long* __restrict__ keys) {
  __shared__ unsigned long long key[512];
  int b = blockIdx.x, tid = threadIdx.x;
  for (int i=tid;i<512;i+=256) {
    int gi = b*512 + i;
    key[i] = (gi < M_CELLS) ? packkey(cs[gi], gi) : 0ULL;
  }
  __syncthreads();
  for (int size=2; size<=512; size<<=1) {
    for (int st=size>>1; st>0; st>>=1) {
      for (int i=tid;i<512;i+=256) {
        int pp = i ^ st;
        if (pp > i) {
          unsigned long long a=key[i], bb=key[pp];
          bool desc = (((b*512+i) & size) == 0);
          if (desc ? (a<bb) : (a>bb)) { key[i]=bb; key[pp]=a; }
        }
      }
      __syncthreads();
    }
  }
  for (int i=tid;i<512;i+=256) keys[b*512+i] = key[i];
}

__global__ __launch_bounds__(1024) void k3b_merge(const unsigned long long* __restrict__ keys,
    const float* __restrict__ summ,
    int* __restrict__ tidx, float* __restrict__ tsc, float* __restrict__ smt) {
  __shared__ unsigned long long key[4096];
  int tid = threadIdx.x;
  for (int i=tid;i<4096;i+=1024) key[i] = keys[i];
  __syncthreads();
  for (int size=1024; size<=4096; size<<=1) {
    for (int st=size>>1; st>0; st>>=1) {
      for (int i=tid;i<4096;i+=1024) {
        int pp = i ^ st;
        if (pp > i) {
          unsigned long long a=key[i], b=key[pp];
          bool desc = ((i & size) == 0);
          if (desc ? (a<b) : (a>b)) { key[i]=b; key[pp]=a; }
        }
      }
      __syncthreads();
    }
  }
  if (tid < 512) {
    if (tid < 500) {
      unsigned long long k = key[tid];
      int idx = (int)(0xFFFFFFFFu - (unsigned)(k & 0xFFFFFFFFull));
      tidx[tid] = idx;
      tsc[tid] = __uint_as_float((unsigned)(k>>32));
      smt[tid] = summ[idx];
    } else { tidx[tid]=0; tsc[tid]=0.f; smt[tid]=0.f; }
  }
}

// ===================== K4: pairwise mask IoU via bitset AND+popcount =====================
__global__ __launch_bounds__(256) void k4_iou(
    const unsigned long long* __restrict__ bits, const int* __restrict__ tidx,
    const int* __restrict__ rmap, const float* __restrict__ smt, float* __restrict__ iou) {
  int ti = blockIdx.y, tj = blockIdx.x;
  int tid = threadIdx.x;
  int ty = tid>>4, tx = tid&15;
  int i = ti*16+ty, j = tj*16+tx;
  if (ti > tj) { if (i<500 && j<500) iou[i*500+j] = 0.f; return; }
  __shared__ unsigned long long A[16][130];
  __shared__ unsigned long long B[16][130];
  __shared__ float sa[16], sb[16];
  if (tid<16) sa[tid] = (ti*16+tid<500) ? smt[ti*16+tid] : 0.f;
  else if (tid<32) sb[tid-16] = (tj*16+tid-16<500) ? smt[tj*16+tid-16] : 0.f;
  int inter = 0;
  for (int half=0; half<2; half++) {
    __syncthreads();
    for (int t=tid;t<2048;t+=256) {
      int r=t>>7, k=t&127;
      int ii = ti*16+r;
      int jj = tj*16+r;
      int ri = (ii<500) ? (rmap ? max(rmap[tidx[ii]],0) : tidx[ii]) : 0;
      int rj = (jj<500) ? (rmap ? max(rmap[tidx[jj]],0) : tidx[jj]) : 0;
      A[r][k] = (ii<500) ? bits[(size_t)ri*256 + half*128 + k] : 0ULL;
      B[r][k] = (jj<500) ? bits[(size_t)rj*256 + half*128 + k] : 0ULL;
    }
    __syncthreads();
    for (int k=0;k<128;k++) inter += __popcll(A[ty][k] & B[tx][k]);
  }
  if (i<500 && j<500) {
    float fi = (float)inter;
    float un = sa[ty] + sb[tx] - fi;
    iou[i*500+j] = (i<j) ? fi / fmaxf(un, 1.f) : 0.f;
  }
}

// ===================== COOP2: k5 + k6 + k7(+Af30 pack) fused (grid 8 x 256) =====================
__global__ __launch_bounds__(256) void coop_nms(
    const float* __restrict__ iou, const float* __restrict__ tsc,
    const int* __restrict__ tidx, float* __restrict__ comp,
    float* __restrict__ nms, int* __restrict__ sel, float* __restrict__ out,
    const float* __restrict__ kfT, _Float16* __restrict__ Af30) {
  cg::grid_group grid = cg::this_grid();
  __shared__ float red[4][64];
  __shared__ float csh[512];
  __shared__ unsigned long long key[512];
  __shared__ int selsh[30];
  int tid = threadIdx.x;
  int tx = tid & 63, ty = tid >> 6;
  // ---- phase k5: comp ----
  {
    int j = blockIdx.x*64 + tx;
    float m0=0.f, m1=0.f, m2=0.f, m3=0.f;
    if (j < 500) {
      int i = ty;
      for (; i+12 < 500; i += 16) {
        m0 = fmaxf(m0, iou[(i   )*500 + j]);
        m1 = fmaxf(m1, iou[(i+ 4)*500 + j]);
        m2 = fmaxf(m2, iou[(i+ 8)*500 + j]);
        m3 = fmaxf(m3, iou[(i+12)*500 + j]);
      }
      for (; i < 500; i += 4) m0 = fmaxf(m0, iou[i*500 + j]);
    }
    float m = fmaxf(fmaxf(m0,m1), fmaxf(m2,m3));
    red[ty][tx] = m;
    __syncthreads();
    if (ty == 0 && j < 512)
      comp[j] = (j < 500) ? fmaxf(fmaxf(red[0][tx],red[1][tx]), fmaxf(red[2][tx],red[3][tx])) : 0.f;
  }
  grid.sync();
  // ---- phase k6: decay ----
  {
    for (int i=tid; i<512; i+=256) csh[i] = (i<500) ? comp[i] : 0.f;
    __syncthreads();
    int j = blockIdx.x*64 + tx;
    float t0=-1e30f, t1=-1e30f, t2=-1e30f, t3=-1e30f;
    if (j < 500) {
      int i = ty;
      for (; i+12 < 500; i += 16) {
        float v0 = iou[(i   )*500 + j], c0 = csh[i];
        float v1 = iou[(i+ 4)*500 + j], c1 = csh[i+4];
        float v2 = iou[(i+ 8)*500 + j], c2 = csh[i+8];
        float v3 = iou[(i+12)*500 + j], c3 = csh[i+12];
        t0 = fmaxf(t0, v0*v0 - c0*c0);
        t1 = fmaxf(t1, v1*v1 - c1*c1);
        t2 = fmaxf(t2, v2*v2 - c2*c2);
        t3 = fmaxf(t3, v3*v3 - c3*c3);
      }
      for (; i < 500; i += 4) { float v = iou[i*500 + j]; float c = csh[i]; t0 = fmaxf(t0, v*v - c*c); }
    }
    float t = fmaxf(fmaxf(t0,t1), fmaxf(t2,t3));
    __syncthreads();
    red[ty][tx] = t;
    __syncthreads();
    if (ty == 0 && j < 512) {
      float o = 0.f;
      if (j < 500) {
        float tt = fmaxf(fmaxf(red[0][tx],red[1][tx]), fmaxf(red[2][tx],red[3][tx]));
        float s = tsc[j] * __expf(-2.f*tt);
        o = (s >= 0.05f) ? s : 0.f;
      }
      nms[j] = o;
    }
  }
  grid.sync();
  // ---- phase k7: top-30 + Af30 pack (block 0) ----
  if (blockIdx.x == 0) {
    for (int i=tid;i<512;i+=256) key[i] = (i<500) ? packkey(nms[i], i) : 0ULL;
    __syncthreads();
    for (int size=2; size<=512; size<<=1) {
      for (int st=size>>1; st>0; st>>=1) {
        for (int i=tid;i<512;i+=256) {
          int pp = i ^ st;
          if (pp > i) {
            unsigned long long a=key[i], b=key[pp];
            bool desc = ((i & size) == 0);
            if (desc ? (a<b) : (a>b)) { key[i]=b; key[pp]=a; }
          }
        }
        __syncthreads();
      }
    }
    if (tid < 30) {
      unsigned long long k = key[tid];
      int j = (int)(0xFFFFFFFFu - (unsigned)(k & 0xFFFFFFFFull));
      float v = __uint_as_float((unsigned)(k>>32));
      out[120+tid] = v;
      out[150+tid] = (v > 0.3f) ? 1.f : 0.f;
      sel[tid] = tidx[j];
      selsh[tid] = tidx[j];
    }
    __syncthreads();
    for (int P = tid; P < 1024; P += 256) {
      int sub = P >> 7, pc = P & 127;
      int ks = sub >> 1, h = sub & 1;
      int mn = pc >> 6, ln = pc & 63;
      int m  = mn*16 + (ln & 15);
      int kb = ks*32 + (ln >> 4)*8;
      half8 o;
      if (m < 30) {
        const float* src = kfT + selsh[m];
        #pragma unroll
        for (int j=0;j<8;j++) {
          float x = src[(size_t)(kb+j)*M_PAD];
          _Float16 hi = (_Float16)x;
          o[j] = h ? (_Float16)(x - (float)hi) : hi;
        }
      } else {
        #pragma unroll
        for (int j=0;j<8;j++) o[j] = (_Float16)0.f;
      }
      *(half8*)&Af30[(size_t)P*8] = o;
    }
  }
}

// ===================== K5/K6/K7 standalone (fallback path) =====================
__global__ __launch_bounds__(256) void k5_comp(const float* __restrict__ iou, float* __restrict__ comp) {
  int tid = threadIdx.x;
  int tx = tid & 63, ty = tid >> 6;
  int j = blockIdx.x*64 + tx;
  float m0=0.f, m1=0.f, m2=0.f, m3=0.f;
  if (j < 500) {
    int i = ty;
    for (; i+12 < 500; i += 16) {
      m0 = fmaxf(m0, iou[(i   )*500 + j]);
      m1 = fmaxf(m1, iou[(i+ 4)*500 + j]);
      m2 = fmaxf(m2, iou[(i+ 8)*500 + j]);
      m3 = fmaxf(m3, iou[(i+12)*500 + j]);
    }
    for (; i < 500; i += 4) m0 = fmaxf(m0, iou[i*500 + j]);
  }
  float m = fmaxf(fmaxf(m0,m1), fmaxf(m2,m3));
  __shared__ float red[4][64];
  red[ty][tx] = m;
  __syncthreads();
  if (ty == 0 && j < 512)
    comp[j] = (j < 500) ? fmaxf(fmaxf(red[0][tx],red[1][tx]), fmaxf(red[2][tx],red[3][tx])) : 0.f;
}

__global__ __launch_bounds__(256) void k6_decay(
    const float* __restrict__ iou, const float* __restrict__ comp,
    const float* __restrict__ tsc, float* __restrict__ nms) {
  __shared__ float csh[512];
  int tid = threadIdx.x;
  for (int i=tid; i<512; i+=256) csh[i] = (i<500) ? comp[i] : 0.f;
  __syncthreads();
  int tx = tid & 63, ty = tid >> 6;
  int j = blockIdx.x*64 + tx;
  float t0=-1e30f, t1=-1e30f, t2=-1e30f, t3=-1e30f;
  if (j < 500) {
    int i = ty;
    for (; i+12 < 500; i += 16) {
      float v0 = iou[(i   )*500 + j], c0 = csh[i];
      float v1 = iou[(i+ 4)*500 + j], c1 = csh[i+4];
      float v2 = iou[(i+ 8)*500 + j], c2 = csh[i+8];
      float v3 = iou[(i+12)*500 + j], c3 = csh[i+12];
      t0 = fmaxf(t0, v0*v0 - c0*c0);
      t1 = fmaxf(t1, v1*v1 - c1*c1);
      t2 = fmaxf(t2, v2*v2 - c2*c2);
      t3 = fmaxf(t3, v3*v3 - c3*c3);
    }
    for (; i < 500; i += 4) { float v = iou[i*500 + j]; float c = csh[i]; t0 = fmaxf(t0, v*v - c*c); }
  }
  float t = fmaxf(fmaxf(t0,t1), fmaxf(t2,t3));
  __shared__ float red[4][64];
  red[ty][tx] = t;
  __syncthreads();
  if (ty == 0 && j < 512) {
    float out = 0.f;
    if (j < 500) {
      float tt = fmaxf(fmaxf(red[0][tx],red[1][tx]), fmaxf(red[2][tx],red[3][tx]));
      float s = tsc[j] * __expf(-2.f*tt);
      out = (s >= 0.05f) ? s : 0.f;
    }
    nms[j] = out;
  }
}

__global__ __launch_bounds__(256) void k7_top30(
    const float* __restrict__ nms, const int* __restrict__ tidx,
    int* __restrict__ sel, float* __restrict__ out,
    const float* __restrict__ kfT, _Float16* __restrict__ Af30) {
  __shared__ unsigned long long key[512];
  __shared__ int selsh[30];
  int tid = threadIdx.x;
  for (int i=tid;i<512;i+=256) key[i] = (i<500) ? packkey(nms[i], i) : 0ULL;
  __syncthreads();
  for (int size=2; size<=512; size<<=1) {
    for (int st=size>>1; st>0; st>>=1) {
      for (int i=tid;i<512;i+=256) {
        int pp = i ^ st;
        if (pp > i) {
          unsigned long long a=key[i], b=key[pp];
          bool desc = ((i & size) == 0);
          if (desc ? (a<b) : (a>b)) { key[i]=b; key[pp]=a; }
        }
      }
      __syncthreads();
    }
  }
  if (tid < 30) {
    unsigned long long k = key[tid];
    int j = (int)(0xFFFFFFFFu - (unsigned)(k & 0xFFFFFFFFull));
    float v = __uint_as_float((unsigned)(k>>32));
    out[120+tid] = v;
    out[150+tid] = (v > 0.3f) ? 1.f : 0.f;
    sel[tid] = tidx[j];
    selsh[tid] = tidx[j];
  }
  __syncthreads();
  if (kfT) {
    for (int P = tid; P < 1024; P += 256) {
      int sub = P >> 7, pc = P & 127;
      int ks = sub >> 1, h = sub & 1;
      int mn = pc >> 6, ln = pc & 63;
      int m  = mn*16 + (ln & 15);
      int kb = ks*32 + (ln >> 4)*8;
      half8 o;
      if (m < 30) {
        const float* src = kfT + selsh[m];
        #pragma unroll
        for (int j=0;j<8;j++) {
          float x = src[(size_t)(kb+j)*M_PAD];
          _Float16 hi = (_Float16)x;
          o[j] = h ? (_Float16)(x - (float)hi) : hi;
        }
      } else {
        #pragma unroll
        for (int j=0;j<8;j++) o[j] = (_Float16)0.f;
      }
      *(half8*)&Af30[(size_t)P*8] = o;
    }
  }
}

// ===================== K8 (MFMA): 32x16384x128 GEMM -> selp probs =====================
__global__ __launch_bounds__(256) void k8_mfma(const _Float16* __restrict__ Af30,
                                               const _Float16* __restrict__ Bf,
                                               float* __restrict__ selp) {
  const int nb = blockIdx.x;
  const int lane = threadIdx.x & 63;
  const int w = threadIdx.x >> 6;
  const half8* A = (const half8*)Af30;                    // [sub][128]
  const half8* B = (const half8*)Bf + (size_t)nb*4096;    // [sub][512]
  f32x4 acc[2][2];
  #pragma unroll
  for (int a=0;a<2;a++)
    #pragma unroll
    for (int b=0;b<2;b++) acc[a][b] = (f32x4){0.f,0.f,0.f,0.f};
  #pragma unroll
  for (int ks=0; ks<4; ks++) {
    half8 ah[2], bh[2], al[2], bl[2];
    #pragma unroll
    for (int mt=0; mt<2; mt++) ah[mt] = A[(ks*2+0)*128 + mt*64 + lane];
    #pragma unroll
    for (int nt=0; nt<2; nt++) bh[nt] = B[(size_t)(ks*2+0)*512 + (w*2+nt)*64 + lane];
    #pragma unroll
    for (int mt=0; mt<2; mt++) al[mt] = A[(ks*2+1)*128 + mt*64 + lane];
    #pragma unroll
    for (int nt=0; nt<2; nt++) bl[nt] = B[(size_t)(ks*2+1)*512 + (w*2+nt)*64 + lane];
    #pragma unroll
    for (int nt=0; nt<2; nt++)
      #pragma unroll
      for (int mt=0; mt<2; mt++) {
        acc[mt][nt] = __builtin_amdgcn_mfma_f32_16x16x32_f16(ah[mt], bh[nt], acc[mt][nt], 0, 0, 0);
        acc[mt][nt] = __builtin_amdgcn_mfma_f32_16x16x32_f16(ah[mt], bl[nt], acc[mt][nt], 0, 0, 0);
        acc[mt][nt] = __builtin_amdgcn_mfma_f32_16x16x32_f16(al[mt], bh[nt], acc[mt][nt], 0, 0, 0);
      }
  }
  const int q = lane >> 4, col = lane & 15;
  #pragma unroll
  for (int mt=0; mt<2; mt++)
    #pragma unroll
    for (int nt=0; nt<2; nt++)
      #pragma unroll
      for (int reg=0; reg<4; reg++) {
        int m = mt*16 + q*4 + reg;
        if (m < 30) {
          int px = nb*128 + w*32 + nt*16 + col;
          float lg = acc[mt][nt][reg];
          selp[(size_t)m*NPIX + px] = __fdividef(1.f, 1.f + __expf(-lg));
        }
      }
}

// ===================== K8 (fallback): probs for 30 selected masks =====================
__global__ __launch_bounds__(256) void k8_selp(
    const float* __restrict__ kf, const float* __restrict__ seg,
    const int* __restrict__ sel, float* __restrict__ selp) {
  int px = blockIdx.x*256 + threadIdx.x;
  int cells[30];
  #pragma unroll
  for (int m=0;m<30;m++) cells[m] = __builtin_amdgcn_readfirstlane(sel[m]);
  float acc[30];
  #pragma unroll
  for (int m=0;m<30;m++) acc[m] = 0.f;
  for (int e=0; e<128; e+=4) {
    float s0 = seg[(size_t)(e+0)*NPIX + px];
    float s1 = seg[(size_t)(e+1)*NPIX + px];
    float s2 = seg[(size_t)(e+2)*NPIX + px];
    float s3 = seg[(size_t)(e+3)*NPIX + px];
    #pragma unroll
    for (int m=0;m<30;m++) {
      const float* kr = kf + (size_t)cells[m]*128 + e;
      acc[m] = fmaf(kr[0], s0, fmaf(kr[1], s1, fmaf(kr[2], s2, fmaf(kr[3], s3, acc[m]))));
    }
  }
  #pragma unroll
  for (int m=0;m<30;m++)
    selp[(size_t)m*NPIX + px] = __fdividef(1.f, 1.f + __expf(-acc[m]));
}

// ===================== COOP3: k9a + k9b fused (grid 512 x 256) =====================
__global__ __launch_bounds__(256) void coop_bbox(const float* __restrict__ selp,
    int* __restrict__ rowmn, int* __restrict__ rowmx, float* __restrict__ out) {
  cg::grid_group grid = cg::this_grid();
  __shared__ float rows[2][128];
  __shared__ int wmn[4], wmx[4];
  __shared__ int r0[256], r1[256], r2[256], r3[256];
  int tid = threadIdx.x;
  // ---- phase A: per-(mask,row) min/max; 512 blocks x 30 units = 15360 exactly ----
  for (int it=0; it<30; it++) {
    int u = it*512 + blockIdx.x;
    int msk = u >> 9, oy = u & 511;
    const float* mp = selp + (size_t)msk*NPIX;
    float yf = fminf(fmaxf((oy+0.5f)*0.25f - 0.5f, 0.f), 127.f);
    int y0 = (int)yf, y1 = min(y0+1,127);
    float fy = yf-(float)y0;
    if (tid < 128) rows[0][tid] = mp[y0*128 + tid];
    else           rows[1][tid-128] = mp[y1*128 + tid-128];
    __syncthreads();
    int mnx = 512, mxx = -1;
    #pragma unroll
    for (int h=0; h<2; h++) {
      int ox = tid + h*256;
      float xf = fminf(fmaxf((ox+0.5f)*0.25f - 0.5f, 0.f), 127.f);
      int x0 = (int)xf, x1 = min(x0+1,127);
      float fx = xf-(float)x0;
      float v0 = rows[0][x0]*(1.f-fx) + rows[0][x1]*fx;
      float v1 = rows[1][x0]*(1.f-fx) + rows[1][x1]*fx;
      float v  = v0*(1.f-fy) + v1*fy;
      if (v > 0.5f) { mnx = min(mnx, ox); mxx = max(mxx, ox); }
    }
    #pragma unroll
    for (int o=32;o>0;o>>=1) {
      mnx = min(mnx, __shfl_down(mnx, o));
      mxx = max(mxx, __shfl_down(mxx, o));
    }
    if ((tid & 63) == 0) { wmn[tid>>6] = mnx; wmx[tid>>6] = mxx; }
    __syncthreads();
    if (tid == 0) {
      rowmn[msk*512 + oy] = min(min(wmn[0],wmn[1]), min(wmn[2],wmn[3]));
      rowmx[msk*512 + oy] = max(max(wmx[0],wmx[1]), max(wmx[2],wmx[3]));
    }
    __syncthreads();
  }
  grid.sync();
  // ---- phase B: reduce 512 rows -> bbox (blocks 0..29, 2 rows/thread) ----
  if (blockIdx.x < 30) {
    int msk = blockIdx.x;
    int mn0 = rowmn[msk*512 + tid],       mx0 = rowmx[msk*512 + tid];
    int mn1 = rowmn[msk*512 + tid + 256], mx1 = rowmx[msk*512 + tid + 256];
    r0[tid] = min(mn0, mn1);
    r1[tid] = max(mx0, mx1);
    r2[tid] = min((mx0>=0)?tid:512, (mx1>=0)?(tid+256):512);
    r3[tid] = max((mx0>=0)?tid:-1,  (mx1>=0)?(tid+256):-1);
    __syncthreads();
    for (int s=128;s>0;s>>=1) {
      if (tid<s) {
        r0[tid]=min(r0[tid],r0[tid+s]); r1[tid]=max(r1[tid],r1[tid+s]);
        r2[tid]=min(r2[tid],r2[tid+s]); r3[tid]=max(r3[tid],r3[tid+s]);
      }
      __syncthreads();
    }
    if (tid==0) {
      bool vis = out[120+msk] > 0.3f;
      out[msk*4+0] = vis ? (float)r0[0] : 0.f;   // xmin (512 if empty, matches ref)
      out[msk*4+1] = vis ? (float)r2[0] : 0.f;   // ymin
      out[msk*4+2] = vis ? (float)r1[0] : 0.f;   // xmax (-1 if empty)
      out[msk*4+3] = vis ? (float)r3[0] : 0.f;   // ymax
    }
  }
}

// ===================== K9a/K9b standalone (fallback path) =====================
__global__ __launch_bounds__(256) void k9a_rows(const float* __restrict__ selp,
                                               int* __restrict__ rowmn, int* __restrict__ rowmx) {
  int msk = blockIdx.y, oy = blockIdx.x;
  const float* mp = selp + (size_t)msk*NPIX;
  __shared__ float rows[2][128];
  __shared__ int wmn[4], wmx[4];
  int tid = threadIdx.x;
  float yf = fminf(fmaxf((oy+0.5f)*0.25f - 0.5f, 0.f), 127.f);
  int y0 = (int)yf, y1 = min(y0+1,127);
  float fy = yf-(float)y0;
  if (tid < 128) rows[0][tid] = mp[y0*128 + tid];
  else           rows[1][tid-128] = mp[y1*128 + tid-128];
  __syncthreads();
  int mnx = 512, mxx = -1;
  #pragma unroll
  for (int h=0; h<2; h++) {
    int ox = tid + h*256;
    float xf = fminf(fmaxf((ox+0.5f)*0.25f - 0.5f, 0.f), 127.f);
    int x0 = (int)xf, x1 = min(x0+1,127);
    float fx = xf-(float)x0;
    float v0 = rows[0][x0]*(1.f-fx) + rows[0][x1]*fx;
    float v1 = rows[1][x0]*(1.f-fx) + rows[1][x1]*fx;
    float v  = v0*(1.f-fy) + v1*fy;
    if (v > 0.5f) { mnx = min(mnx, ox); mxx = max(mxx, ox); }
  }
  #pragma unroll
  for (int o=32;o>0;o>>=1) {
    mnx = min(mnx, __shfl_down(mnx, o));
    mxx = max(mxx, __shfl_down(mxx, o));
  }
  if ((tid & 63) == 0) { wmn[tid>>6] = mnx; wmx[tid>>6] = mxx; }
  __syncthreads();
  if (tid == 0) {
    rowmn[msk*512 + oy] = min(min(wmn[0],wmn[1]), min(wmn[2],wmn[3]));
    rowmx[msk*512 + oy] = max(max(wmx[0],wmx[1]), max(wmx[2],wmx[3]));
  }
}

__global__ __launch_bounds__(512) void k9b_box(const int* __restrict__ rowmn,
                                              const int* __restrict__ rowmx, float* out) {
  int msk = blockIdx.x, tid = threadIdx.x;
  __shared__ int r0[512], r1[512], r2[512], r3[512];
  int mn = rowmn[msk*512 + tid];
  int mx = rowmx[msk*512 + tid];
  bool occ = (mx >= 0);
  r0[tid] = mn;
  r1[tid] = mx;
  r2[tid] = occ ? tid : 512;
  r3[tid] = occ ? tid : -1;
  __syncthreads();
  for (int s=256;s>0;s>>=1) {
    if (tid<s) {
      r0[tid]=min(r0[tid],r0[tid+s]); r1[tid]=max(r1[tid],r1[tid+s]);
      r2[tid]=min(r2[tid],r2[tid+s]); r3[tid]=max(r3[tid],r3[tid+s]);
    }
    __syncthreads();
  }
  if (tid==0) {
    bool vis = out[120+msk] > 0.3f;
    out[msk*4+0] = vis ? (float)r0[0] : 0.f;
    out[msk*4+1] = vis ? (float)r2[0] : 0.f;
    out[msk*4+2] = vis ? (float)r1[0] : 0.f;
    out[msk*4+3] = vis ? (float)r3[0] : 0.f;
  }
}

// ===================== launch =====================
extern "C" void kernel_launch(void* const* d_in, const int* in_sizes, int n_in,
                              void* d_out, int out_size, void* d_ws, size_t ws_size,
                              hipStream_t stream) {
  (void)in_sizes; (void)n_in; (void)out_size;
  if (ws_size < WS_FB) return;
  const float* cate[5]; const float* kern[5];
  for (int i=0;i<5;i++){ cate[i]=(const float*)d_in[2*i]; kern[i]=(const float*)d_in[2*i+1]; }
  const float* seg = (const float*)d_in[10];
  char* ws = (char*)d_ws;
  float* out = (float*)d_out;

  const bool mfma = (ws_size >= WS_MFMA);

  float* kf      = (float*)(ws + (mfma ? B_KF   : F_KF));   // MFMA path: kfT e-major
  float* scores  = (float*)(ws + (mfma ? B_SC   : F_SC));
  float* summ    = (float*)(ws + (mfma ? B_SM   : F_SM));
  float* cs      = (float*)(ws + (mfma ? B_CS   : F_CS));
  unsigned long long* bits = (unsigned long long*)(ws + (mfma ? B_BIT : F_BIT));
  float* spp     = (float*)(ws + (mfma ? B_SPP  : F_SPP));
  int*   tidx    = (int*)(ws + (mfma ? B_TIDX : F_TIDX));
  float* tsc     = (float*)(ws + (mfma ? B_TSC  : F_TSC));
  float* smt     = (float*)(ws + (mfma ? B_SMT  : F_SMT));
  float* iou     = (float*)(ws + (mfma ? B_IOU  : F_IOU));
  float* comp    = (float*)(ws + (mfma ? B_COMP : F_COMP));
  float* nms     = (float*)(ws + (mfma ? B_NMS  : F_NMS));
  int*   sel     = (int*)(ws + (mfma ? B_SEL  : F_SEL));
  float* selp    = (float*)(ws + (mfma ? B_SELP : F_SELP));
  int*   rowmn   = (int*)(ws + (mfma ? B_RMN  : F_RMN));
  int*   rowmx   = (int*)(ws + (mfma ? B_RMX  : F_RMX));
  unsigned long long* keys = (unsigned long long*)(ws + (mfma ? B_KEYS : F_KEYS));

  if (mfma) {
    _Float16* Af = (_Float16*)(ws + B_AFR);
    _Float16* Bf = (_Float16*)(ws + B_BFR);
    _Float16* Af30 = (_Float16*)(ws + B_AF30);
    int* cmap = (int*)(ws + B_CMAP);
    int* rmap = (int*)(ws + B_RMAP);
    int* vcnt = (int*)(ws + B_VCNT);
    hipMemsetAsync(vcnt, 0, 4, stream);
    k0aT_gather<<<dim3(800,5), 256, 0, stream>>>(cate[0],cate[1],cate[2],cate[3],cate[4],
                                      kern[0],kern[1],kern[2],kern[3],kern[4],
                                      kf, scores, cmap, rmap, vcnt);
    k0c_bfrag<<<128*4096/256, 256, 0, stream>>>(seg, Bf);
    k0b_afrag<<<31*4096/256, 256, 0, stream>>>(kf, cmap, vcnt, Af);
    k1_mfma  <<<dim3(31, 128), 256, 0, stream>>>(Af, Bf, vcnt, bits, spp);
    {
      const unsigned long long* bitsc = bits;
      const float* sppc = spp; const float* scoresc = scores; const int* rmapc = rmap;
      void* p[] = { (void*)&bitsc, (void*)&sppc, (void*)&scoresc, (void*)&rmapc,
                    (void*)&summ, (void*)&cs, (void*)&keys, (void*)&tidx, (void*)&tsc, (void*)&smt };
      hipLaunchCooperativeKernel((const void*)coop_sort, dim3(242), dim3(1024), p, 0, stream);
    }
    k4_iou   <<<dim3(32,32), 256, 0, stream>>>(bits, tidx, rmap, smt, iou);
    {
      const float* iouc = iou; const float* tscc = tsc; const int* tidxc = tidx;
      const float* kfc = kf;
      void* p[] = { (void*)&iouc, (void*)&tscc, (void*)&tidxc, (void*)&comp,
                    (void*)&nms, (void*)&sel, (void*)&out, (void*)&kfc, (void*)&Af30 };
      hipLaunchCooperativeKernel((const void*)coop_nms, dim3(8), dim3(256), p, 0, stream);
    }
    k8_mfma  <<<128, 256, 0, stream>>>(Af30, Bf, selp);
    {
      const float* selpc = selp;
      void* p[] = { (void*)&selpc, (void*)&rowmn, (void*)&rowmx, (void*)&out };
      hipLaunchCooperativeKernel((const void*)coop_bbox, dim3(512), dim3(256), p, 0, stream);
    }
  } else {
    k0a_gather<<<dim3(800,5), 256, 0, stream>>>(cate[0],cate[1],cate[2],cate[3],cate[4],
                                      kern[0],kern[1],kern[2],kern[3],kern[4], kf, scores);
    k1_gemm  <<<dim3(64,121), 256, 0, stream>>>(kf, seg, bits, spp);
    k2_cscore<<<M_CELLS/4, 256, 0, stream>>>(bits, spp, scores, summ, cs, 64, M_CELLS);
    k3a_sort512<<<8, 256, 0, stream>>>(cs, keys);
    k3b_merge  <<<1, 1024, 0, stream>>>(keys, summ, tidx, tsc, smt);
    k4_iou   <<<dim3(32,32), 256, 0, stream>>>(bits, tidx, nullptr, smt, iou);
    k5_comp  <<<8, 256, 0, stream>>>(iou, comp);
    k6_decay <<<8, 256, 0, stream>>>(iou, comp, tsc, nms);
    k7_top30 <<<1, 256, 0, stream>>>(nms, tidx, sel, out, nullptr, nullptr);
    k8_selp  <<<NPIX/256, 256, 0, stream>>>(kf, seg, sel, selp);
    k9a_rows <<<dim3(512,30), 256, 0, stream>>>(selp, rowmn, rowmx);
    k9b_box  <<<30, 512, 0, stream>>>(rowmn, rowmx, out);
  }
}

// Round 13
// 290.449 us; speedup vs baseline: 1.4962x; 1.4962x over previous
//
#include <hip/hip_runtime.h>
#include <math.h>

#define M_CELLS 3872
#define M_PAD   3968   // 31 * 128
#define NPIX    16384  // 128*128

typedef _Float16 half8 __attribute__((ext_vector_type(8)));
typedef float f32x4 __attribute__((ext_vector_type(4)));

// async global->LDS 16B: per-lane global addr, wave-uniform LDS base (+lane*16 in HW)
#define GL2LDS(g, l) __builtin_amdgcn_global_load_lds( \
    (const __attribute__((address_space(1))) unsigned int*)(g), \
    (__attribute__((address_space(3))) unsigned int*)(l), 16, 0, 0)

// NOTE (round 12 post-mortem): cg::grid.sync() costs ~25-30 µs on gfx950 (device-scope
// coherence across 8 non-coherent per-XCD L2s). Kernel-boundary dependencies are CHEAPER
// than in-kernel grid sync on CDNA4 — do not re-introduce cooperative fusion here.

// ===================== workspace layouts =====================
static constexpr size_t ALN(size_t x){ return (x + 255) & ~(size_t)255; }

// ---- fallback layout ----
static constexpr size_t F_KF   = 0;
static constexpr size_t F_SC   = F_KF + (size_t)M_CELLS*128*4;
static constexpr size_t F_SM   = F_SC + (size_t)M_CELLS*4;
static constexpr size_t F_CS   = F_SM + (size_t)M_CELLS*4;
static constexpr size_t F_BIT  = F_CS + (size_t)M_CELLS*4;
static constexpr size_t F_SPP  = F_BIT + (size_t)M_CELLS*256*8;
static constexpr size_t F_TIDX = F_SPP + (size_t)64*M_CELLS*4;
static constexpr size_t F_TSC  = F_TIDX + 512*4;
static constexpr size_t F_SMT  = F_TSC + 512*4;
static constexpr size_t F_IOU  = F_SMT + 512*4;
static constexpr size_t F_COMP = F_IOU + (size_t)500*500*4;
static constexpr size_t F_NMS  = F_COMP + 512*4;
static constexpr size_t F_SEL  = F_NMS + 512*4;
static constexpr size_t F_SELP = F_SEL + 32*4;
static constexpr size_t F_RMN  = ALN(F_SELP + (size_t)30*NPIX*4);   // int[30*512] per-row min-x
static constexpr size_t F_RMX  = F_RMN + 30*512*4;                  // int[30*512] per-row max-x
static constexpr size_t F_KEYS = ALN(F_RMX + 30*512*4);
static constexpr size_t WS_FB  = F_KEYS + 4096*8;

// ---- MFMA layout (~25 MB, proven to fit in rounds 2-12) ----
static constexpr size_t B_KF   = 0;                                       // float kfT[128][M_PAD] e-major
static constexpr size_t B_AFR  = ALN(B_KF  + (size_t)M_PAD*128*4);        // frag A: [31][8 sub][512 pc][16B] = 2MB
static constexpr size_t B_BFR  = ALN(B_AFR + (size_t)31*4096*16);         // frag B: [128][8 sub][512 pc][16B] = 8MB
static constexpr size_t B_SC   = ALN(B_BFR + (size_t)128*4096*16);
static constexpr size_t B_SM   = ALN(B_SC + (size_t)M_PAD*4);
static constexpr size_t B_CS   = ALN(B_SM + (size_t)M_PAD*4);
static constexpr size_t B_BIT  = ALN(B_CS + (size_t)M_PAD*4);
static constexpr size_t B_SPP  = ALN(B_BIT + (size_t)M_PAD*256*8);
static constexpr size_t B_TIDX = ALN(B_SPP + (size_t)128*M_PAD*4);
static constexpr size_t B_TSC  = ALN(B_TIDX + 512*4);
static constexpr size_t B_SMT  = ALN(B_TSC + 512*4);
static constexpr size_t B_IOU  = ALN(B_SMT + 512*4);
static constexpr size_t B_COMP = ALN(B_IOU + (size_t)500*500*4);
static constexpr size_t B_NMS  = ALN(B_COMP + 512*4);
static constexpr size_t B_SEL  = ALN(B_NMS + 512*4);
static constexpr size_t B_SELP = ALN(B_SEL + 32*4);
static constexpr size_t B_RMN  = ALN(B_SELP + (size_t)30*NPIX*4);
static constexpr size_t B_RMX  = B_RMN + 30*512*4;
static constexpr size_t B_CMAP = ALN(B_RMX + 30*512*4);   // int[4096] newIdx -> cell
static constexpr size_t B_RMAP = B_CMAP + 4096*4;         // int[4096] cell -> newIdx | -1
static constexpr size_t B_VCNT = B_RMAP + 4096*4;         // int[64]
static constexpr size_t B_KEYS = ALN(B_VCNT + 64*4);      // u64[4096]
static constexpr size_t B_AF30 = ALN(B_KEYS + 4096*8);    // frag A30: [8 sub][128 pc][16B] = 16KB
static constexpr size_t WS_MFMA = B_AF30 + 8*128*16;

__device__ inline unsigned long long packkey(float v, int i) {
  return ((unsigned long long)__float_as_uint(v) << 32) | (unsigned)(0xFFFFFFFFu - (unsigned)i);
}

// ===================== K0aT (MFMA): gather kernels e-major + scores + inline compaction =====================
__global__ __launch_bounds__(256) void k0aT_gather(
    const float* __restrict__ c0,const float* __restrict__ c1,const float* __restrict__ c2,
    const float* __restrict__ c3,const float* __restrict__ c4,
    const float* __restrict__ w0,const float* __restrict__ w1,const float* __restrict__ w2,
    const float* __restrict__ w3,const float* __restrict__ w4,
    float* __restrict__ kfT, float* __restrict__ scores,
    int* __restrict__ cmap, int* __restrict__ rmap, int* __restrict__ vcnt) {
  const int lvl = blockIdx.y;
  const int Gs[5]   = {1600,1296,576,256,144};
  const int offs[5] = {0,1600,2896,3472,3728};
  const int G = Gs[lvl], off = offs[lvl];
  const float* kl = (lvl==0)?w0:(lvl==1)?w1:(lvl==2)?w2:(lvl==3)?w3:w4;
  const float* cl = (lvl==0)?c0:(lvl==1)?c1:(lvl==2)?c2:(lvl==3)?c3:c4;
  int t = blockIdx.x*256 + threadIdx.x;
  if (t >= G*128) return;
  int e = t / G, c = t - e*G;
  kfT[(size_t)e*M_PAD + off + c] = kl[t];
  if (e == 0) {
    int cell = off + c;
    float sc = cl[c];
    scores[cell] = sc;
    if (sc > 0.3f) {
      int run = atomicAdd(vcnt, 1);
      cmap[run] = cell;
      rmap[cell] = run;
    } else rmap[cell] = -1;
  }
}

// ===================== K0a (fallback): row-major kf =====================
__global__ __launch_bounds__(256) void k0a_gather(
    const float* __restrict__ c0,const float* __restrict__ c1,const float* __restrict__ c2,
    const float* __restrict__ c3,const float* __restrict__ c4,
    const float* __restrict__ w0,const float* __restrict__ w1,const float* __restrict__ w2,
    const float* __restrict__ w3,const float* __restrict__ w4,
    float* __restrict__ kf, float* __restrict__ scores) {
  const int lvl = blockIdx.y;
  const int Gs[5]   = {1600,1296,576,256,144};
  const int offs[5] = {0,1600,2896,3472,3728};
  const int G = Gs[lvl], off = offs[lvl];
  const float* kl = (lvl==0)?w0:(lvl==1)?w1:(lvl==2)?w2:(lvl==3)?w3:w4;
  const float* cl = (lvl==0)?c0:(lvl==1)?c1:(lvl==2)?c2:(lvl==3)?c3:c4;
  int t = blockIdx.x*256 + threadIdx.x;
  if (t >= G*128) return;
  int e = t / G, c = t - e*G;
  kf[(size_t)(off+c)*128 + e] = kl[t];
  if (e == 0) scores[off+c] = cl[c];
}

// ===================== K0b: kfT -> frag-ordered A (compacted rows) =====================
__global__ __launch_bounds__(256) void k0b_afrag(const float* __restrict__ kfT,
                                                 const int* __restrict__ cmap,
                                                 const int* __restrict__ vcnt,
                                                 _Float16* __restrict__ Af) {
  int P = blockIdx.x*256 + threadIdx.x;     // 31*4096 = 126976
  int mblock = P >> 12;
  int r  = P & 4095;
  int sub = r >> 9, pc = r & 511;
  int ks = sub >> 1, h = sub & 1;
  int mn = pc >> 6, ln = pc & 63;
  int mcomp = mblock*128 + mn*16 + (ln & 15);
  int kb = ks*32 + (ln >> 4)*8;
  half8 o;
  if (mcomp < vcnt[0]) {
    const float* src = kfT + cmap[mcomp];
    #pragma unroll
    for (int j=0;j<8;j++) {
      float x = src[(size_t)(kb+j)*M_PAD];
      _Float16 hi = (_Float16)x;
      o[j] = h ? (_Float16)(x - (float)hi) : hi;
    }
  } else {
    #pragma unroll
    for (int j=0;j<8;j++) o[j] = (_Float16)0.f;
  }
  *(half8*)&Af[(size_t)P*8] = o;
}

// ===================== K0c: seg -> frag-ordered B =====================
__global__ __launch_bounds__(256) void k0c_bfrag(const float* __restrict__ seg,
                                                 _Float16* __restrict__ Bf) {
  int P = blockIdx.x*256 + threadIdx.x;     // 128*4096 = 524288
  int nb = P >> 12;
  int r  = P & 4095;
  int sub = r >> 9, pc = r & 511;
  int ks = sub >> 1, h = sub & 1;
  int mn = pc >> 6, ln = pc & 63;
  int px = nb*128 + mn*16 + (ln & 15);
  int kb = ks*32 + (ln >> 4)*8;
  half8 o;
  #pragma unroll
  for (int j=0;j<8;j++) {
    float x = seg[(size_t)(kb+j)*NPIX + px];
    _Float16 hi = (_Float16)x;
    o[j] = h ? (_Float16)(x - (float)hi) : hi;
  }
  *(half8*)&Bf[(size_t)P*8] = o;
}

// ===================== K1 (fallback): fp32 vector GEMM =====================
__global__ __launch_bounds__(256, 6) void k1_gemm(
    const float* __restrict__ kf, const float* __restrict__ seg,
    unsigned long long* __restrict__ bits, float* __restrict__ spp) {
  int tid = threadIdx.x;
  int p  = blockIdx.x*256 + tid;
  int c0 = blockIdx.y*32;
  float acc[32];
  #pragma unroll
  for (int c=0;c<32;c++) acc[c]=0.f;
  for (int ch=0; ch<8; ch++) {
    float s[16];
    #pragma unroll
    for (int e=0;e<16;e++) s[e] = seg[(size_t)(ch*16+e)*NPIX + p];
    #pragma unroll
    for (int c=0;c<32;c++) {
      float a=0.f;
      #pragma unroll
      for (int e=0;e<16;e++) a = fmaf(kf[(size_t)(c0+c)*128 + ch*16 + e], s[e], a);
      acc[c] += a;
    }
  }
  int wv = tid>>6, ln = tid&63;
  __shared__ float wsum[32][4];
  #pragma unroll
  for (int c=0;c<32;c++) {
    float logit = acc[c];
    bool msk = logit > 0.f;
    unsigned long long bal = __ballot(msk);
    float pr = msk ? __fdividef(1.f, 1.f + __expf(-logit)) : 0.f;
    #pragma unroll
    for (int o=32;o>0;o>>=1) pr += __shfl_down(pr, o);
    if (ln==0) {
      bits[(size_t)(c0+c)*256 + blockIdx.x*4 + wv] = bal;
      wsum[c][wv] = pr;
    }
  }
  __syncthreads();
  if (tid < 32)
    spp[(size_t)blockIdx.x*M_CELLS + c0 + tid] = wsum[tid][0]+wsum[tid][1]+wsum[tid][2]+wsum[tid][3];
}

// ===================== K1 (MFMA): compacted rows; 16KB sub-steps, dbuf, (256,4) =====================
// NOTE: (256,5) forced VGPR 64->48 and spilled acc to scratch (431MB HBM writes, 2.2x slower).
// (256,4) keeps VGPR=64, no spill — measured 60 µs. Do not raise min-waves here.
__global__ __launch_bounds__(256, 4) void k1_mfma(
    const _Float16* __restrict__ Af, const _Float16* __restrict__ Bf,
    const int* __restrict__ vcnt,
    unsigned long long* __restrict__ bits, float* __restrict__ spp) {
  if (blockIdx.x*128 >= vcnt[0]) return;   // compacted tail: no valid rows
  __shared__ char lds[32768];   // 2 x (A 8KB | B 8KB)
  const int tid  = threadIdx.x;
  const int lane = tid & 63;
  const int wave = tid >> 6;
  const int wr = wave >> 1, wc = wave & 1;
  const char* gA = (const char*)Af + (size_t)blockIdx.x*65536;
  const char* gB = (const char*)Bf + (size_t)blockIdx.y*65536;

  f32x4 acc[4][4];
  #pragma unroll
  for (int a=0;a<4;a++)
    #pragma unroll
    for (int b=0;b<4;b++) acc[a][b] = (f32x4){0.f,0.f,0.f,0.f};

  auto issue = [&](int sub, int buf) {
    const char* ga = gA + sub*8192;
    const char* gb = gB + sub*8192;
    char* la = &lds[buf*16384];
    char* lb = &lds[buf*16384 + 8192];
    GL2LDS(ga +  wave   *1024 + lane*16, la +  wave   *1024);
    GL2LDS(ga + (wave+4)*1024 + lane*16, la + (wave+4)*1024);
    GL2LDS(gb +  wave   *1024 + lane*16, lb +  wave   *1024);
    GL2LDS(gb + (wave+4)*1024 + lane*16, lb + (wave+4)*1024);
  };

  issue(0, 0);
  half8 ah[4], bh[4];
  #pragma unroll
  for (int s=0; s<8; s++) {
    __syncthreads();
    if (s < 7) issue(s+1, (s+1)&1);
    const char* lb_ = &lds[(s&1)*16384];
    if ((s & 1) == 0) {
      #pragma unroll
      for (int mt=0; mt<4; mt++) ah[mt] = *(const half8*)&lb_[(wr*4+mt)*1024 + lane*16];
      #pragma unroll
      for (int nt=0; nt<4; nt++) bh[nt] = *(const half8*)&lb_[8192 + (wc*4+nt)*1024 + lane*16];
      #pragma unroll
      for (int nt=0; nt<4; nt++)
        #pragma unroll
        for (int mt=0; mt<4; mt++)
          acc[mt][nt] = __builtin_amdgcn_mfma_f32_16x16x32_f16(ah[mt], bh[nt], acc[mt][nt], 0, 0, 0);
    } else {
      #pragma unroll
      for (int nt=0; nt<4; nt++) {
        half8 bl = *(const half8*)&lb_[8192 + (wc*4+nt)*1024 + lane*16];
        #pragma unroll
        for (int mt=0; mt<4; mt++)
          acc[mt][nt] = __builtin_amdgcn_mfma_f32_16x16x32_f16(ah[mt], bl, acc[mt][nt], 0, 0, 0);
      }
      #pragma unroll
      for (int mt=0; mt<4; mt++) {
        half8 al = *(const half8*)&lb_[(wr*4+mt)*1024 + lane*16];
        #pragma unroll
        for (int nt=0; nt<4; nt++)
          acc[mt][nt] = __builtin_amdgcn_mfma_f32_16x16x32_f16(al, bh[nt], acc[mt][nt], 0, 0, 0);
      }
    }
  }
  __syncthreads();

  const int q = lane >> 4, mm = lane & 15;
  const int mbase = blockIdx.x * 128;
  const int wordIdx = blockIdx.y*2 + wc;
  float* ldsf = (float*)lds;
  #pragma unroll
  for (int mt=0; mt<4; mt++) {
    #pragma unroll
    for (int reg=0; reg<4; reg++) {
      unsigned long long bal[4];
      float ps = 0.f;
      #pragma unroll
      for (int nt=0; nt<4; nt++) {
        float lg = acc[mt][nt][reg];
        bal[nt] = __ballot(lg > 0.f);
        if (lg > 0.f) ps += __fdividef(1.f, 1.f + __expf(-lg));
      }
      ps += __shfl_xor(ps, 1); ps += __shfl_xor(ps, 2);
      ps += __shfl_xor(ps, 4); ps += __shfl_xor(ps, 8);
      if (mm == 0) {
        int cl = wr*64 + mt*16 + q*4 + reg;
        unsigned long long wd = 0;
        #pragma unroll
        for (int nt=0; nt<4; nt++)
          wd |= ((bal[nt] >> (q*16)) & 0xFFFFull) << (nt*16);
        bits[(size_t)(mbase + cl)*256 + wordIdx] = wd;
        ldsf[cl*2 + wc] = ps;
      }
    }
  }
  __syncthreads();
  if (tid < 128)
    spp[(size_t)blockIdx.y*M_PAD + mbase + tid] = ldsf[tid*2] + ldsf[tid*2+1];
}

// ===================== K2 (compact): sum_masks + seg_score + cscore via rmap =====================
__global__ __launch_bounds__(256) void k2c_cscore(
    const unsigned long long* __restrict__ bits, const float* __restrict__ spp,
    const float* __restrict__ scores, const int* __restrict__ rmap,
    float* __restrict__ summ, float* __restrict__ cs) {
  int cell = blockIdx.x*4 + (threadIdx.x>>6);
  int ln = threadIdx.x & 63;
  int ridx = rmap[cell];
  if (ridx < 0) { if (ln==0) { summ[cell]=0.f; cs[cell]=0.f; } return; }
  const unsigned long long* row = bits + (size_t)ridx*256;
  int cnt = 0;
  #pragma unroll
  for (int k=0;k<4;k++) cnt += __popcll(row[ln + 64*k]);
  float sp = 0.f;
  for (int i=ln; i<128; i+=64) sp += spp[(size_t)i*M_PAD + ridx];
  #pragma unroll
  for (int o=32;o>0;o>>=1) { cnt += __shfl_down(cnt,o); sp += __shfl_down(sp,o); }
  if (ln==0) {
    float smf = (float)cnt;
    float sc = scores[cell];
    float strd = (cell<1600)?4.f:(cell<2896)?8.f:(cell<3472)?16.f:(cell<3728)?32.f:64.f;
    bool keep = (smf > strd);
    float ss = sp / fmaxf(smf, 1.f);
    summ[cell] = smf;
    cs[cell] = keep ? sc*ss : 0.f;
  }
}

// ===================== K2 (fallback): original full version =====================
__global__ __launch_bounds__(256) void k2_cscore(
    const unsigned long long* __restrict__ bits, const float* __restrict__ spp,
    const float* __restrict__ scores, float* __restrict__ summ, float* __restrict__ cs,
    int nparts, int mp) {
  int cell = blockIdx.x*4 + (threadIdx.x>>6);
  int ln = threadIdx.x & 63;
  const unsigned long long* row = bits + (size_t)cell*256;
  int cnt = 0;
  #pragma unroll
  for (int k=0;k<4;k++) cnt += __popcll(row[ln + 64*k]);
  float sp = 0.f;
  for (int i=ln; i<nparts; i+=64) sp += spp[(size_t)i*mp + cell];
  #pragma unroll
  for (int o=32;o>0;o>>=1) { cnt += __shfl_down(cnt,o); sp += __shfl_down(sp,o); }
  if (ln==0) {
    float smf = (float)cnt;
    float sc = scores[cell];
    float strd = (cell<1600)?4.f:(cell<2896)?8.f:(cell<3472)?16.f:(cell<3728)?32.f:64.f;
    bool keep = (sc > 0.3f) && (smf > strd);
    float ss = sp / fmaxf(smf, 1.f);
    summ[cell] = smf;
    cs[cell] = keep ? sc*ss : 0.f;
  }
}

// ===================== K3a: bitonic sizes 2..512 on 8 parallel 512-segments =====================
__global__ __launch_bounds__(256) void k3a_sort512(const float* __restrict__ cs,
                                                   unsigned long long* __restrict__ keys) {
  __shared__ unsigned long long key[512];
  int b = blockIdx.x, tid = threadIdx.x;
  for (int i=tid;i<512;i+=256) {
    int gi = b*512 + i;
    key[i] = (gi < M_CELLS) ? packkey(cs[gi], gi) : 0ULL;
  }
  __syncthreads();
  for (int size=2; size<=512; size<<=1) {
    for (int st=size>>1; st>0; st>>=1) {
      for (int i=tid;i<512;i+=256) {
        int pp = i ^ st;
        if (pp > i) {
          unsigned long long a=key[i], bb=key[pp];
          bool desc = (((b*512+i) & size) == 0);
          if (desc ? (a<bb) : (a>bb)) { key[i]=bb; key[pp]=a; }
        }
      }
      __syncthreads();
    }
  }
  for (int i=tid;i<512;i+=256) keys[b*512+i] = key[i];
}

// ===================== K3b: bitonic sizes 1024..4096 merge + emit top500 =====================
__global__ __launch_bounds__(1024) void k3b_merge(const unsigned long long* __restrict__ keys,
    const float* __restrict__ summ,
    int* __restrict__ tidx, float* __restrict__ tsc, float* __restrict__ smt) {
  __shared__ unsigned long long key[4096];
  int tid = threadIdx.x;
  for (int i=tid;i<4096;i+=1024) key[i] = keys[i];
  __syncthreads();
  for (int size=1024; size<=4096; size<<=1) {
    for (int st=size>>1; st>0; st>>=1) {
      for (int i=tid;i<4096;i+=1024) {
        int pp = i ^ st;
        if (pp > i) {
          unsigned long long a=key[i], b=key[pp];
          bool desc = ((i & size) == 0);
          if (desc ? (a<b) : (a>b)) { key[i]=b; key[pp]=a; }
        }
      }
      __syncthreads();
    }
  }
  if (tid < 512) {
    if (tid < 500) {
      unsigned long long k = key[tid];
      int idx = (int)(0xFFFFFFFFu - (unsigned)(k & 0xFFFFFFFFull));
      tidx[tid] = idx;
      tsc[tid] = __uint_as_float((unsigned)(k>>32));
      smt[tid] = summ[idx];
    } else { tidx[tid]=0; tsc[tid]=0.f; smt[tid]=0.f; }
  }
}

// ===================== K4: pairwise mask IoU via bitset AND+popcount =====================
__global__ __launch_bounds__(256) void k4_iou(
    const unsigned long long* __restrict__ bits, const int* __restrict__ tidx,
    const int* __restrict__ rmap, const float* __restrict__ smt, float* __restrict__ iou) {
  int ti = blockIdx.y, tj = blockIdx.x;
  int tid = threadIdx.x;
  int ty = tid>>4, tx = tid&15;
  int i = ti*16+ty, j = tj*16+tx;
  if (ti > tj) { if (i<500 && j<500) iou[i*500+j] = 0.f; return; }
  __shared__ unsigned long long A[16][130];
  __shared__ unsigned long long B[16][130];
  __shared__ float sa[16], sb[16];
  if (tid<16) sa[tid] = (ti*16+tid<500) ? smt[ti*16+tid] : 0.f;
  else if (tid<32) sb[tid-16] = (tj*16+tid-16<500) ? smt[tj*16+tid-16] : 0.f;
  int inter = 0;
  for (int half=0; half<2; half++) {
    __syncthreads();
    for (int t=tid;t<2048;t+=256) {
      int r=t>>7, k=t&127;
      int ii = ti*16+r;
      int jj = tj*16+r;
      int ri = (ii<500) ? (rmap ? max(rmap[tidx[ii]],0) : tidx[ii]) : 0;
      int rj = (jj<500) ? (rmap ? max(rmap[tidx[jj]],0) : tidx[jj]) : 0;
      A[r][k] = (ii<500) ? bits[(size_t)ri*256 + half*128 + k] : 0ULL;
      B[r][k] = (jj<500) ? bits[(size_t)rj*256 + half*128 + k] : 0ULL;
    }
    __syncthreads();
    for (int k=0;k<128;k++) inter += __popcll(A[ty][k] & B[tx][k]);
  }
  if (i<500 && j<500) {
    float fi = (float)inter;
    float un = sa[ty] + sb[tx] - fi;
    iou[i*500+j] = (i<j) ? fi / fmaxf(un, 1.f) : 0.f;
  }
}

// ===================== K5: comp[j] = max_i iou[i][j] — parallel + ILP =====================
__global__ __launch_bounds__(256) void k5_comp(const float* __restrict__ iou, float* __restrict__ comp) {
  int tid = threadIdx.x;
  int tx = tid & 63, ty = tid >> 6;
  int j = blockIdx.x*64 + tx;
  float m0=0.f, m1=0.f, m2=0.f, m3=0.f;
  if (j < 500) {
    int i = ty;
    for (; i+12 < 500; i += 16) {
      m0 = fmaxf(m0, iou[(i   )*500 + j]);
      m1 = fmaxf(m1, iou[(i+ 4)*500 + j]);
      m2 = fmaxf(m2, iou[(i+ 8)*500 + j]);
      m3 = fmaxf(m3, iou[(i+12)*500 + j]);
    }
    for (; i < 500; i += 4) m0 = fmaxf(m0, iou[i*500 + j]);
  }
  float m = fmaxf(fmaxf(m0,m1), fmaxf(m2,m3));
  __shared__ float red[4][64];
  red[ty][tx] = m;
  __syncthreads();
  if (ty == 0 && j < 512)
    comp[j] = (j < 500) ? fmaxf(fmaxf(red[0][tx],red[1][tx]), fmaxf(red[2][tx],red[3][tx])) : 0.f;
}

// ===================== K6: decay + threshold — parallel + ILP =====================
__global__ __launch_bounds__(256) void k6_decay(
    const float* __restrict__ iou, const float* __restrict__ comp,
    const float* __restrict__ tsc, float* __restrict__ nms) {
  __shared__ float csh[512];
  int tid = threadIdx.x;
  for (int i=tid; i<512; i+=256) csh[i] = (i<500) ? comp[i] : 0.f;
  __syncthreads();
  int tx = tid & 63, ty = tid >> 6;
  int j = blockIdx.x*64 + tx;
  float t0=-1e30f, t1=-1e30f, t2=-1e30f, t3=-1e30f;
  if (j < 500) {
    int i = ty;
    for (; i+12 < 500; i += 16) {
      float v0 = iou[(i   )*500 + j], c0 = csh[i];
      float v1 = iou[(i+ 4)*500 + j], c1 = csh[i+4];
      float v2 = iou[(i+ 8)*500 + j], c2 = csh[i+8];
      float v3 = iou[(i+12)*500 + j], c3 = csh[i+12];
      t0 = fmaxf(t0, v0*v0 - c0*c0);
      t1 = fmaxf(t1, v1*v1 - c1*c1);
      t2 = fmaxf(t2, v2*v2 - c2*c2);
      t3 = fmaxf(t3, v3*v3 - c3*c3);
    }
    for (; i < 500; i += 4) { float v = iou[i*500 + j]; float c = csh[i]; t0 = fmaxf(t0, v*v - c*c); }
  }
  float t = fmaxf(fmaxf(t0,t1), fmaxf(t2,t3));
  __shared__ float red[4][64];
  red[ty][tx] = t;
  __syncthreads();
  if (ty == 0 && j < 512) {
    float out = 0.f;
    if (j < 500) {
      float tt = fmaxf(fmaxf(red[0][tx],red[1][tx]), fmaxf(red[2][tx],red[3][tx]));
      float s = tsc[j] * __expf(-2.f*tt);
      out = (s >= 0.05f) ? s : 0.f;
    }
    nms[j] = out;
  }
}

// ===================== K7: top-30 (+ fused Af30 pack when kfT != null) =====================
__global__ __launch_bounds__(256) void k7_top30(
    const float* __restrict__ nms, const int* __restrict__ tidx,
    int* __restrict__ sel, float* __restrict__ out,
    const float* __restrict__ kfT, _Float16* __restrict__ Af30) {
  __shared__ unsigned long long key[512];
  __shared__ int selsh[30];
  int tid = threadIdx.x;
  for (int i=tid;i<512;i+=256) key[i] = (i<500) ? packkey(nms[i], i) : 0ULL;
  __syncthreads();
  for (int size=2; size<=512; size<<=1) {
    for (int st=size>>1; st>0; st>>=1) {
      for (int i=tid;i<512;i+=256) {
        int pp = i ^ st;
        if (pp > i) {
          unsigned long long a=key[i], b=key[pp];
          bool desc = ((i & size) == 0);
          if (desc ? (a<b) : (a>b)) { key[i]=b; key[pp]=a; }
        }
      }
      __syncthreads();
    }
  }
  if (tid < 30) {
    unsigned long long k = key[tid];
    int j = (int)(0xFFFFFFFFu - (unsigned)(k & 0xFFFFFFFFull));
    float v = __uint_as_float((unsigned)(k>>32));
    out[120+tid] = v;
    out[150+tid] = (v > 0.3f) ? 1.f : 0.f;
    sel[tid] = tidx[j];
    selsh[tid] = tidx[j];
  }
  __syncthreads();
  if (kfT) {
    for (int P = tid; P < 1024; P += 256) {
      int sub = P >> 7, pc = P & 127;
      int ks = sub >> 1, h = sub & 1;
      int mn = pc >> 6, ln = pc & 63;
      int m  = mn*16 + (ln & 15);
      int kb = ks*32 + (ln >> 4)*8;
      half8 o;
      if (m < 30) {
        const float* src = kfT + selsh[m];
        #pragma unroll
        for (int j=0;j<8;j++) {
          float x = src[(size_t)(kb+j)*M_PAD];
          _Float16 hi = (_Float16)x;
          o[j] = h ? (_Float16)(x - (float)hi) : hi;
        }
      } else {
        #pragma unroll
        for (int j=0;j<8;j++) o[j] = (_Float16)0.f;
      }
      *(half8*)&Af30[(size_t)P*8] = o;
    }
  }
}

// ===================== K8 (MFMA): 32x16384x128 GEMM -> selp probs =====================
__global__ __launch_bounds__(256) void k8_mfma(const _Float16* __restrict__ Af30,
                                               const _Float16* __restrict__ Bf,
                                               float* __restrict__ selp) {
  const int nb = blockIdx.x;
  const int lane = threadIdx.x & 63;
  const int w = threadIdx.x >> 6;
  const half8* A = (const half8*)Af30;                    // [sub][128]
  const half8* B = (const half8*)Bf + (size_t)nb*4096;    // [sub][512]
  f32x4 acc[2][2];
  #pragma unroll
  for (int a=0;a<2;a++)
    #pragma unroll
    for (int b=0;b<2;b++) acc[a][b] = (f32x4){0.f,0.f,0.f,0.f};
  #pragma unroll
  for (int ks=0; ks<4; ks++) {
    half8 ah[2], bh[2], al[2], bl[2];
    #pragma unroll
    for (int mt=0; mt<2; mt++) ah[mt] = A[(ks*2+0)*128 + mt*64 + lane];
    #pragma unroll
    for (int nt=0; nt<2; nt++) bh[nt] = B[(size_t)(ks*2+0)*512 + (w*2+nt)*64 + lane];
    #pragma unroll
    for (int mt=0; mt<2; mt++) al[mt] = A[(ks*2+1)*128 + mt*64 + lane];
    #pragma unroll
    for (int nt=0; nt<2; nt++) bl[nt] = B[(size_t)(ks*2+1)*512 + (w*2+nt)*64 + lane];
    #pragma unroll
    for (int nt=0; nt<2; nt++)
      #pragma unroll
      for (int mt=0; mt<2; mt++) {
        acc[mt][nt] = __builtin_amdgcn_mfma_f32_16x16x32_f16(ah[mt], bh[nt], acc[mt][nt], 0, 0, 0);
        acc[mt][nt] = __builtin_amdgcn_mfma_f32_16x16x32_f16(ah[mt], bl[nt], acc[mt][nt], 0, 0, 0);
        acc[mt][nt] = __builtin_amdgcn_mfma_f32_16x16x32_f16(al[mt], bh[nt], acc[mt][nt], 0, 0, 0);
      }
  }
  const int q = lane >> 4, col = lane & 15;
  #pragma unroll
  for (int mt=0; mt<2; mt++)
    #pragma unroll
    for (int nt=0; nt<2; nt++)
      #pragma unroll
      for (int reg=0; reg<4; reg++) {
        int m = mt*16 + q*4 + reg;
        if (m < 30) {
          int px = nb*128 + w*32 + nt*16 + col;
          float lg = acc[mt][nt][reg];
          selp[(size_t)m*NPIX + px] = __fdividef(1.f, 1.f + __expf(-lg));
        }
      }
}

// ===================== K8 (fallback): probs for 30 selected masks =====================
__global__ __launch_bounds__(256) void k8_selp(
    const float* __restrict__ kf, const float* __restrict__ seg,
    const int* __restrict__ sel, float* __restrict__ selp) {
  int px = blockIdx.x*256 + threadIdx.x;
  int cells[30];
  #pragma unroll
  for (int m=0;m<30;m++) cells[m] = __builtin_amdgcn_readfirstlane(sel[m]);
  float acc[30];
  #pragma unroll
  for (int m=0;m<30;m++) acc[m] = 0.f;
  for (int e=0; e<128; e+=4) {
    float s0 = seg[(size_t)(e+0)*NPIX + px];
    float s1 = seg[(size_t)(e+1)*NPIX + px];
    float s2 = seg[(size_t)(e+2)*NPIX + px];
    float s3 = seg[(size_t)(e+3)*NPIX + px];
    #pragma unroll
    for (int m=0;m<30;m++) {
      const float* kr = kf + (size_t)cells[m]*128 + e;
      acc[m] = fmaf(kr[0], s0, fmaf(kr[1], s1, fmaf(kr[2], s2, fmaf(kr[3], s3, acc[m]))));
    }
  }
  #pragma unroll
  for (int m=0;m<30;m++)
    selp[(size_t)m*NPIX + px] = __fdividef(1.f, 1.f + __expf(-acc[m]));
}

// ===================== K9a: 8 output rows per block -> per-row min/max =====================
// grid (64, 30). The 8 output rows oy0..oy0+7 span <=4 source rows (yf stride 0.25):
// stage 4 rows once, 16 px/thread. 8x fewer blocks than per-row version.
__global__ __launch_bounds__(256) void k9a_rows8(const float* __restrict__ selp,
                                                int* __restrict__ rowmn, int* __restrict__ rowmx) {
  int msk = blockIdx.y, oy0 = blockIdx.x * 8;
  const float* mp = selp + (size_t)msk*NPIX;
  __shared__ float rows[4][128];
  __shared__ int wmn[8][4], wmx[8][4];
  int tid = threadIdx.x;
  float yf0 = fminf(fmaxf((oy0+0.5f)*0.25f - 0.5f, 0.f), 127.f);
  int y_base = (int)yf0;
  {
    int r = tid >> 7, c = tid & 127;
    rows[r][c]     = mp[min(y_base + r,     127)*128 + c];
    rows[r + 2][c] = mp[min(y_base + r + 2, 127)*128 + c];
  }
  __syncthreads();
  int mnx[8], mxx[8];
  #pragma unroll
  for (int i=0;i<8;i++) { mnx[i] = 512; mxx[i] = -1; }
  #pragma unroll
  for (int h=0; h<2; h++) {
    int ox = tid + h*256;
    float xf = fminf(fmaxf((ox+0.5f)*0.25f - 0.5f, 0.f), 127.f);
    int x0 = (int)xf, x1 = min(x0+1,127);
    float fx = xf-(float)x0;
    #pragma unroll
    for (int i=0;i<8;i++) {
      int oy = oy0 + i;
      float yf = fminf(fmaxf((oy+0.5f)*0.25f - 0.5f, 0.f), 127.f);
      int y0 = (int)yf, y1 = min(y0+1,127);
      float fy = yf-(float)y0;
      const float* ra = rows[y0 - y_base];
      const float* rb = rows[y1 - y_base];
      float v0 = ra[x0]*(1.f-fx) + ra[x1]*fx;
      float v1 = rb[x0]*(1.f-fx) + rb[x1]*fx;
      float v  = v0*(1.f-fy) + v1*fy;
      if (v > 0.5f) { mnx[i] = min(mnx[i], ox); mxx[i] = max(mxx[i], ox); }
    }
  }
  #pragma unroll
  for (int i=0;i<8;i++) {
    int a = mnx[i], b = mxx[i];
    #pragma unroll
    for (int o=32;o>0;o>>=1) {
      a = min(a, __shfl_down(a, o));
      b = max(b, __shfl_down(b, o));
    }
    if ((tid & 63) == 0) { wmn[i][tid>>6] = a; wmx[i][tid>>6] = b; }
  }
  __syncthreads();
  if (tid < 8) {
    rowmn[msk*512 + oy0 + tid] = min(min(wmn[tid][0],wmn[tid][1]), min(wmn[tid][2],wmn[tid][3]));
    rowmx[msk*512 + oy0 + tid] = max(max(wmx[tid][0],wmx[tid][1]), max(wmx[tid][2],wmx[tid][3]));
  }
}

// ===================== K9b: per-row results -> bbox (LDS tree reduce) =====================
__global__ __launch_bounds__(512) void k9b_box(const int* __restrict__ rowmn,
                                              const int* __restrict__ rowmx, float* out) {
  int msk = blockIdx.x, tid = threadIdx.x;
  __shared__ int r0[512], r1[512], r2[512], r3[512];
  int mn = rowmn[msk*512 + tid];
  int mx = rowmx[msk*512 + tid];
  bool occ = (mx >= 0);
  r0[tid] = mn;
  r1[tid] = mx;
  r2[tid] = occ ? tid : 512;
  r3[tid] = occ ? tid : -1;
  __syncthreads();
  for (int s=256;s>0;s>>=1) {
    if (tid<s) {
      r0[tid]=min(r0[tid],r0[tid+s]); r1[tid]=max(r1[tid],r1[tid+s]);
      r2[tid]=min(r2[tid],r2[tid+s]); r3[tid]=max(r3[tid],r3[tid+s]);
    }
    __syncthreads();
  }
  if (tid==0) {
    bool vis = out[120+msk] > 0.3f;
    out[msk*4+0] = vis ? (float)r0[0] : 0.f;   // xmin (512 if empty, matches ref)
    out[msk*4+1] = vis ? (float)r2[0] : 0.f;   // ymin
    out[msk*4+2] = vis ? (float)r1[0] : 0.f;   // xmax (-1 if empty)
    out[msk*4+3] = vis ? (float)r3[0] : 0.f;   // ymax
  }
}

// ===================== launch =====================
extern "C" void kernel_launch(void* const* d_in, const int* in_sizes, int n_in,
                              void* d_out, int out_size, void* d_ws, size_t ws_size,
                              hipStream_t stream) {
  (void)in_sizes; (void)n_in; (void)out_size;
  if (ws_size < WS_FB) return;
  const float* cate[5]; const float* kern[5];
  for (int i=0;i<5;i++){ cate[i]=(const float*)d_in[2*i]; kern[i]=(const float*)d_in[2*i+1]; }
  const float* seg = (const float*)d_in[10];
  char* ws = (char*)d_ws;
  float* out = (float*)d_out;

  const bool mfma = (ws_size >= WS_MFMA);

  float* kf      = (float*)(ws + (mfma ? B_KF   : F_KF));   // MFMA path: kfT e-major
  float* scores  = (float*)(ws + (mfma ? B_SC   : F_SC));
  float* summ    = (float*)(ws + (mfma ? B_SM   : F_SM));
  float* cs      = (float*)(ws + (mfma ? B_CS   : F_CS));
  unsigned long long* bits = (unsigned long long*)(ws + (mfma ? B_BIT : F_BIT));
  float* spp     = (float*)(ws + (mfma ? B_SPP  : F_SPP));
  int*   tidx    = (int*)(ws + (mfma ? B_TIDX : F_TIDX));
  float* tsc     = (float*)(ws + (mfma ? B_TSC  : F_TSC));
  float* smt     = (float*)(ws + (mfma ? B_SMT  : F_SMT));
  float* iou     = (float*)(ws + (mfma ? B_IOU  : F_IOU));
  float* comp    = (float*)(ws + (mfma ? B_COMP : F_COMP));
  float* nms     = (float*)(ws + (mfma ? B_NMS  : F_NMS));
  int*   sel     = (int*)(ws + (mfma ? B_SEL  : F_SEL));
  float* selp    = (float*)(ws + (mfma ? B_SELP : F_SELP));
  int*   rowmn   = (int*)(ws + (mfma ? B_RMN  : F_RMN));
  int*   rowmx   = (int*)(ws + (mfma ? B_RMX  : F_RMX));
  unsigned long long* keys = (unsigned long long*)(ws + (mfma ? B_KEYS : F_KEYS));

  if (mfma) {
    _Float16* Af = (_Float16*)(ws + B_AFR);
    _Float16* Bf = (_Float16*)(ws + B_BFR);
    _Float16* Af30 = (_Float16*)(ws + B_AF30);
    int* cmap = (int*)(ws + B_CMAP);
    int* rmap = (int*)(ws + B_RMAP);
    int* vcnt = (int*)(ws + B_VCNT);
    hipMemsetAsync(vcnt, 0, 4, stream);
    k0aT_gather<<<dim3(800,5), 256, 0, stream>>>(cate[0],cate[1],cate[2],cate[3],cate[4],
                                      kern[0],kern[1],kern[2],kern[3],kern[4],
                                      kf, scores, cmap, rmap, vcnt);
    k0c_bfrag<<<128*4096/256, 256, 0, stream>>>(seg, Bf);
    k0b_afrag<<<31*4096/256, 256, 0, stream>>>(kf, cmap, vcnt, Af);
    k1_mfma  <<<dim3(31, 128), 256, 0, stream>>>(Af, Bf, vcnt, bits, spp);
    k2c_cscore<<<M_CELLS/4, 256, 0, stream>>>(bits, spp, scores, rmap, summ, cs);
    k3a_sort512<<<8, 256, 0, stream>>>(cs, keys);
    k3b_merge  <<<1, 1024, 0, stream>>>(keys, summ, tidx, tsc, smt);
    k4_iou   <<<dim3(32,32), 256, 0, stream>>>(bits, tidx, rmap, smt, iou);
    k5_comp  <<<8, 256, 0, stream>>>(iou, comp);
    k6_decay <<<8, 256, 0, stream>>>(iou, comp, tsc, nms);
    k7_top30 <<<1, 256, 0, stream>>>(nms, tidx, sel, out, kf, Af30);
    k8_mfma  <<<128, 256, 0, stream>>>(Af30, Bf, selp);
  } else {
    k0a_gather<<<dim3(800,5), 256, 0, stream>>>(cate[0],cate[1],cate[2],cate[3],cate[4],
                                      kern[0],kern[1],kern[2],kern[3],kern[4], kf, scores);
    k1_gemm  <<<dim3(64,121), 256, 0, stream>>>(kf, seg, bits, spp);
    k2_cscore<<<M_CELLS/4, 256, 0, stream>>>(bits, spp, scores, summ, cs, 64, M_CELLS);
    k3a_sort512<<<8, 256, 0, stream>>>(cs, keys);
    k3b_merge  <<<1, 1024, 0, stream>>>(keys, summ, tidx, tsc, smt);
    k4_iou   <<<dim3(32,32), 256, 0, stream>>>(bits, tidx, nullptr, smt, iou);
    k5_comp  <<<8, 256, 0, stream>>>(iou, comp);
    k6_decay <<<8, 256, 0, stream>>>(iou, comp, tsc, nms);
    k7_top30 <<<1, 256, 0, stream>>>(nms, tidx, sel, out, nullptr, nullptr);
    k8_selp  <<<NPIX/256, 256, 0, stream>>>(kf, seg, sel, selp);
  }
  k9a_rows8<<<dim3(64,30), 256, 0, stream>>>(selp, rowmn, rowmx);
  k9b_box  <<<30, 512, 0, stream>>>(rowmn, rowmx, out);
}

// Round 14
// 283.364 us; speedup vs baseline: 1.5336x; 1.0250x over previous
//
#include <hip/hip_runtime.h>
#include <math.h>

#define M_CELLS 3872
#define M_PAD   3968   // 31 * 128
#define NPIX    16384  // 128*128

typedef _Float16 half8 __attribute__((ext_vector_type(8)));
typedef float f32x4 __attribute__((ext_vector_type(4)));

// async global->LDS 16B: per-lane global addr, wave-uniform LDS base (+lane*16 in HW)
#define GL2LDS(g, l) __builtin_amdgcn_global_load_lds( \
    (const __attribute__((address_space(1))) unsigned int*)(g), \
    (__attribute__((address_space(3))) unsigned int*)(l), 16, 0, 0)

// NOTE (round 12): cg::grid.sync() costs ~25-30 µs on gfx950 (device-scope coherence across
// 8 non-coherent per-XCD L2s). Kernel-boundary deps are CHEAPER than in-kernel grid sync.
// NOTE (round 13): k9a 8-rows-per-block variant regressed ~12 µs vs per-row blocks; reverted.

// ===================== workspace layouts =====================
static constexpr size_t ALN(size_t x){ return (x + 255) & ~(size_t)255; }

// ---- fallback layout ----
static constexpr size_t F_KF   = 0;
static constexpr size_t F_SC   = F_KF + (size_t)M_CELLS*128*4;
static constexpr size_t F_SM   = F_SC + (size_t)M_CELLS*4;
static constexpr size_t F_CS   = F_SM + (size_t)M_CELLS*4;
static constexpr size_t F_BIT  = F_CS + (size_t)M_CELLS*4;
static constexpr size_t F_SPP  = F_BIT + (size_t)M_CELLS*256*8;
static constexpr size_t F_TIDX = F_SPP + (size_t)64*M_CELLS*4;
static constexpr size_t F_TSC  = F_TIDX + 512*4;
static constexpr size_t F_SMT  = F_TSC + 512*4;
static constexpr size_t F_IOU  = F_SMT + 512*4;
static constexpr size_t F_COMP = F_IOU + (size_t)500*500*4;
static constexpr size_t F_NMS  = F_COMP + 512*4;
static constexpr size_t F_SEL  = F_NMS + 512*4;
static constexpr size_t F_SELP = F_SEL + 32*4;
static constexpr size_t F_RMN  = ALN(F_SELP + (size_t)30*NPIX*4);   // int[30*512] per-row min-x
static constexpr size_t F_RMX  = F_RMN + 30*512*4;                  // int[30*512] per-row max-x
static constexpr size_t F_KEYS = ALN(F_RMX + 30*512*4);
static constexpr size_t WS_FB  = F_KEYS + 4096*8;

// ---- MFMA layout (~25 MB, proven to fit in rounds 2-13) ----
static constexpr size_t B_KF   = 0;                                       // float kfT[128][M_PAD] e-major
static constexpr size_t B_AFR  = ALN(B_KF  + (size_t)M_PAD*128*4);        // frag A: [31][8 sub][512 pc][16B] = 2MB
static constexpr size_t B_BFR  = ALN(B_AFR + (size_t)31*4096*16);         // frag B: [128][8 sub][512 pc][16B] = 8MB
static constexpr size_t B_SC   = ALN(B_BFR + (size_t)128*4096*16);
static constexpr size_t B_SM   = ALN(B_SC + (size_t)M_PAD*4);
static constexpr size_t B_CS   = ALN(B_SM + (size_t)M_PAD*4);
static constexpr size_t B_BIT  = ALN(B_CS + (size_t)M_PAD*4);
static constexpr size_t B_SPP  = ALN(B_BIT + (size_t)M_PAD*256*8);
static constexpr size_t B_TIDX = ALN(B_SPP + (size_t)128*M_PAD*4);
static constexpr size_t B_TSC  = ALN(B_TIDX + 512*4);
static constexpr size_t B_SMT  = ALN(B_TSC + 512*4);
static constexpr size_t B_IOU  = ALN(B_SMT + 512*4);
static constexpr size_t B_COMP = ALN(B_IOU + (size_t)500*500*4);
static constexpr size_t B_NMS  = ALN(B_COMP + 512*4);
static constexpr size_t B_SEL  = ALN(B_NMS + 512*4);
static constexpr size_t B_SELP = ALN(B_SEL + 32*4);
static constexpr size_t B_RMN  = ALN(B_SELP + (size_t)30*NPIX*4);
static constexpr size_t B_RMX  = B_RMN + 30*512*4;
static constexpr size_t B_CMAP = ALN(B_RMX + 30*512*4);   // int[4096] newIdx -> cell
static constexpr size_t B_RMAP = B_CMAP + 4096*4;         // int[4096] cell -> newIdx | -1
static constexpr size_t B_VCNT = B_RMAP + 4096*4;         // int[64]
static constexpr size_t B_KEYS = ALN(B_VCNT + 64*4);      // u64[4096]
static constexpr size_t B_AF30 = ALN(B_KEYS + 4096*8);    // frag A30: [8 sub][128 pc][16B] = 16KB
static constexpr size_t WS_MFMA = B_AF30 + 8*128*16;

__device__ inline unsigned long long packkey(float v, int i) {
  return ((unsigned long long)__float_as_uint(v) << 32) | (unsigned)(0xFFFFFFFFu - (unsigned)i);
}

// ===================== K0_fused: (k0aT gather+compact) + (k0c B-frag) in ONE dispatch ==========
// The two halves are data-independent (kern/cate vs seg; disjoint outputs) -> blockIdx partition.
// blocks [0,2048): B-frag pieces. blocks [2048,6048): kfT gather + scores + compaction.
__global__ __launch_bounds__(256) void k0_fused(
    const float* __restrict__ c0,const float* __restrict__ c1,const float* __restrict__ c2,
    const float* __restrict__ c3,const float* __restrict__ c4,
    const float* __restrict__ w0,const float* __restrict__ w1,const float* __restrict__ w2,
    const float* __restrict__ w3,const float* __restrict__ w4,
    const float* __restrict__ seg,
    float* __restrict__ kfT, float* __restrict__ scores,
    int* __restrict__ cmap, int* __restrict__ rmap, int* __restrict__ vcnt,
    _Float16* __restrict__ Bf) {
  int b = blockIdx.x;
  if (b < 2048) {
    // ---- k0c body: seg -> frag-ordered B ----
    int P = b*256 + threadIdx.x;     // 128*4096 = 524288
    int nb = P >> 12;
    int r  = P & 4095;
    int sub = r >> 9, pc = r & 511;
    int ks = sub >> 1, h = sub & 1;
    int mn = pc >> 6, ln = pc & 63;
    int px = nb*128 + mn*16 + (ln & 15);
    int kb = ks*32 + (ln >> 4)*8;
    half8 o;
    #pragma unroll
    for (int j=0;j<8;j++) {
      float x = seg[(size_t)(kb+j)*NPIX + px];
      _Float16 hi = (_Float16)x;
      o[j] = h ? (_Float16)(x - (float)hi) : hi;
    }
    *(half8*)&Bf[(size_t)P*8] = o;
  } else {
    // ---- k0aT body: gather e-major + scores + inline compaction ----
    int bb = b - 2048;                // 4000 blocks = 800 x 5
    int lvl = bb / 800, bx = bb - lvl*800;
    const int Gs[5]   = {1600,1296,576,256,144};
    const int offs[5] = {0,1600,2896,3472,3728};
    const int G = Gs[lvl], off = offs[lvl];
    const float* kl = (lvl==0)?w0:(lvl==1)?w1:(lvl==2)?w2:(lvl==3)?w3:w4;
    const float* cl = (lvl==0)?c0:(lvl==1)?c1:(lvl==2)?c2:(lvl==3)?c3:c4;
    int t = bx*256 + threadIdx.x;
    if (t >= G*128) return;
    int e = t / G, c = t - e*G;
    kfT[(size_t)e*M_PAD + off + c] = kl[t];
    if (e == 0) {
      int cell = off + c;
      float sc = cl[c];
      scores[cell] = sc;
      if (sc > 0.3f) {
        int run = atomicAdd(vcnt, 1);
        cmap[run] = cell;
        rmap[cell] = run;
      } else rmap[cell] = -1;
    }
  }
}

// ===================== K0a (fallback): row-major kf =====================
__global__ __launch_bounds__(256) void k0a_gather(
    const float* __restrict__ c0,const float* __restrict__ c1,const float* __restrict__ c2,
    const float* __restrict__ c3,const float* __restrict__ c4,
    const float* __restrict__ w0,const float* __restrict__ w1,const float* __restrict__ w2,
    const float* __restrict__ w3,const float* __restrict__ w4,
    float* __restrict__ kf, float* __restrict__ scores) {
  const int lvl = blockIdx.y;
  const int Gs[5]   = {1600,1296,576,256,144};
  const int offs[5] = {0,1600,2896,3472,3728};
  const int G = Gs[lvl], off = offs[lvl];
  const float* kl = (lvl==0)?w0:(lvl==1)?w1:(lvl==2)?w2:(lvl==3)?w3:w4;
  const float* cl = (lvl==0)?c0:(lvl==1)?c1:(lvl==2)?c2:(lvl==3)?c3:c4;
  int t = blockIdx.x*256 + threadIdx.x;
  if (t >= G*128) return;
  int e = t / G, c = t - e*G;
  kf[(size_t)(off+c)*128 + e] = kl[t];
  if (e == 0) scores[off+c] = cl[c];
}

// ===================== K0b: kfT -> frag-ordered A (compacted rows) =====================
__global__ __launch_bounds__(256) void k0b_afrag(const float* __restrict__ kfT,
                                                 const int* __restrict__ cmap,
                                                 const int* __restrict__ vcnt,
                                                 _Float16* __restrict__ Af) {
  int P = blockIdx.x*256 + threadIdx.x;     // 31*4096 = 126976
  int mblock = P >> 12;
  int r  = P & 4095;
  int sub = r >> 9, pc = r & 511;
  int ks = sub >> 1, h = sub & 1;
  int mn = pc >> 6, ln = pc & 63;
  int mcomp = mblock*128 + mn*16 + (ln & 15);
  int kb = ks*32 + (ln >> 4)*8;
  half8 o;
  if (mcomp < vcnt[0]) {
    const float* src = kfT + cmap[mcomp];
    #pragma unroll
    for (int j=0;j<8;j++) {
      float x = src[(size_t)(kb+j)*M_PAD];
      _Float16 hi = (_Float16)x;
      o[j] = h ? (_Float16)(x - (float)hi) : hi;
    }
  } else {
    #pragma unroll
    for (int j=0;j<8;j++) o[j] = (_Float16)0.f;
  }
  *(half8*)&Af[(size_t)P*8] = o;
}

// ===================== K0c standalone (fallback helper, unused in MFMA path) ==================
__global__ __launch_bounds__(256) void k0c_bfrag(const float* __restrict__ seg,
                                                 _Float16* __restrict__ Bf) {
  int P = blockIdx.x*256 + threadIdx.x;
  int nb = P >> 12;
  int r  = P & 4095;
  int sub = r >> 9, pc = r & 511;
  int ks = sub >> 1, h = sub & 1;
  int mn = pc >> 6, ln = pc & 63;
  int px = nb*128 + mn*16 + (ln & 15);
  int kb = ks*32 + (ln >> 4)*8;
  half8 o;
  #pragma unroll
  for (int j=0;j<8;j++) {
    float x = seg[(size_t)(kb+j)*NPIX + px];
    _Float16 hi = (_Float16)x;
    o[j] = h ? (_Float16)(x - (float)hi) : hi;
  }
  *(half8*)&Bf[(size_t)P*8] = o;
}

// ===================== K1 (fallback): fp32 vector GEMM =====================
__global__ __launch_bounds__(256, 6) void k1_gemm(
    const float* __restrict__ kf, const float* __restrict__ seg,
    unsigned long long* __restrict__ bits, float* __restrict__ spp) {
  int tid = threadIdx.x;
  int p  = blockIdx.x*256 + tid;
  int c0 = blockIdx.y*32;
  float acc[32];
  #pragma unroll
  for (int c=0;c<32;c++) acc[c]=0.f;
  for (int ch=0; ch<8; ch++) {
    float s[16];
    #pragma unroll
    for (int e=0;e<16;e++) s[e] = seg[(size_t)(ch*16+e)*NPIX + p];
    #pragma unroll
    for (int c=0;c<32;c++) {
      float a=0.f;
      #pragma unroll
      for (int e=0;e<16;e++) a = fmaf(kf[(size_t)(c0+c)*128 + ch*16 + e], s[e], a);
      acc[c] += a;
    }
  }
  int wv = tid>>6, ln = tid&63;
  __shared__ float wsum[32][4];
  #pragma unroll
  for (int c=0;c<32;c++) {
    float logit = acc[c];
    bool msk = logit > 0.f;
    unsigned long long bal = __ballot(msk);
    float pr = msk ? __fdividef(1.f, 1.f + __expf(-logit)) : 0.f;
    #pragma unroll
    for (int o=32;o>0;o>>=1) pr += __shfl_down(pr, o);
    if (ln==0) {
      bits[(size_t)(c0+c)*256 + blockIdx.x*4 + wv] = bal;
      wsum[c][wv] = pr;
    }
  }
  __syncthreads();
  if (tid < 32)
    spp[(size_t)blockIdx.x*M_CELLS + c0 + tid] = wsum[tid][0]+wsum[tid][1]+wsum[tid][2]+wsum[tid][3];
}

// ===================== K1 (MFMA): compacted rows; 16KB sub-steps, dbuf, (256,4) =====================
// NOTE: (256,5) forced VGPR 64->48 and spilled acc to scratch (431MB HBM writes, 2.2x slower).
// (256,4) keeps VGPR=64, no spill — measured 60 µs. Do not raise min-waves here.
__global__ __launch_bounds__(256, 4) void k1_mfma(
    const _Float16* __restrict__ Af, const _Float16* __restrict__ Bf,
    const int* __restrict__ vcnt,
    unsigned long long* __restrict__ bits, float* __restrict__ spp) {
  if (blockIdx.x*128 >= vcnt[0]) return;   // compacted tail: no valid rows
  __shared__ char lds[32768];   // 2 x (A 8KB | B 8KB)
  const int tid  = threadIdx.x;
  const int lane = tid & 63;
  const int wave = tid >> 6;
  const int wr = wave >> 1, wc = wave & 1;
  const char* gA = (const char*)Af + (size_t)blockIdx.x*65536;
  const char* gB = (const char*)Bf + (size_t)blockIdx.y*65536;

  f32x4 acc[4][4];
  #pragma unroll
  for (int a=0;a<4;a++)
    #pragma unroll
    for (int b=0;b<4;b++) acc[a][b] = (f32x4){0.f,0.f,0.f,0.f};

  auto issue = [&](int sub, int buf) {
    const char* ga = gA + sub*8192;
    const char* gb = gB + sub*8192;
    char* la = &lds[buf*16384];
    char* lb = &lds[buf*16384 + 8192];
    GL2LDS(ga +  wave   *1024 + lane*16, la +  wave   *1024);
    GL2LDS(ga + (wave+4)*1024 + lane*16, la + (wave+4)*1024);
    GL2LDS(gb +  wave   *1024 + lane*16, lb +  wave   *1024);
    GL2LDS(gb + (wave+4)*1024 + lane*16, lb + (wave+4)*1024);
  };

  issue(0, 0);
  half8 ah[4], bh[4];
  #pragma unroll
  for (int s=0; s<8; s++) {
    __syncthreads();
    if (s < 7) issue(s+1, (s+1)&1);
    const char* lb_ = &lds[(s&1)*16384];
    if ((s & 1) == 0) {
      #pragma unroll
      for (int mt=0; mt<4; mt++) ah[mt] = *(const half8*)&lb_[(wr*4+mt)*1024 + lane*16];
      #pragma unroll
      for (int nt=0; nt<4; nt++) bh[nt] = *(const half8*)&lb_[8192 + (wc*4+nt)*1024 + lane*16];
      #pragma unroll
      for (int nt=0; nt<4; nt++)
        #pragma unroll
        for (int mt=0; mt<4; mt++)
          acc[mt][nt] = __builtin_amdgcn_mfma_f32_16x16x32_f16(ah[mt], bh[nt], acc[mt][nt], 0, 0, 0);
    } else {
      #pragma unroll
      for (int nt=0; nt<4; nt++) {
        half8 bl = *(const half8*)&lb_[8192 + (wc*4+nt)*1024 + lane*16];
        #pragma unroll
        for (int mt=0; mt<4; mt++)
          acc[mt][nt] = __builtin_amdgcn_mfma_f32_16x16x32_f16(ah[mt], bl, acc[mt][nt], 0, 0, 0);
      }
      #pragma unroll
      for (int mt=0; mt<4; mt++) {
        half8 al = *(const half8*)&lb_[(wr*4+mt)*1024 + lane*16];
        #pragma unroll
        for (int nt=0; nt<4; nt++)
          acc[mt][nt] = __builtin_amdgcn_mfma_f32_16x16x32_f16(al, bh[nt], acc[mt][nt], 0, 0, 0);
      }
    }
  }
  __syncthreads();

  const int q = lane >> 4, mm = lane & 15;
  const int mbase = blockIdx.x * 128;
  const int wordIdx = blockIdx.y*2 + wc;
  float* ldsf = (float*)lds;
  #pragma unroll
  for (int mt=0; mt<4; mt++) {
    #pragma unroll
    for (int reg=0; reg<4; reg++) {
      unsigned long long bal[4];
      float ps = 0.f;
      #pragma unroll
      for (int nt=0; nt<4; nt++) {
        float lg = acc[mt][nt][reg];
        bal[nt] = __ballot(lg > 0.f);
        if (lg > 0.f) ps += __fdividef(1.f, 1.f + __expf(-lg));
      }
      ps += __shfl_xor(ps, 1); ps += __shfl_xor(ps, 2);
      ps += __shfl_xor(ps, 4); ps += __shfl_xor(ps, 8);
      if (mm == 0) {
        int cl = wr*64 + mt*16 + q*4 + reg;
        unsigned long long wd = 0;
        #pragma unroll
        for (int nt=0; nt<4; nt++)
          wd |= ((bal[nt] >> (q*16)) & 0xFFFFull) << (nt*16);
        bits[(size_t)(mbase + cl)*256 + wordIdx] = wd;
        ldsf[cl*2 + wc] = ps;
      }
    }
  }
  __syncthreads();
  if (tid < 128)
    spp[(size_t)blockIdx.y*M_PAD + mbase + tid] = ldsf[tid*2] + ldsf[tid*2+1];
}

// ===================== K2 (compact): sum_masks + seg_score + cscore via rmap =====================
__global__ __launch_bounds__(256) void k2c_cscore(
    const unsigned long long* __restrict__ bits, const float* __restrict__ spp,
    const float* __restrict__ scores, const int* __restrict__ rmap,
    float* __restrict__ summ, float* __restrict__ cs) {
  int cell = blockIdx.x*4 + (threadIdx.x>>6);
  int ln = threadIdx.x & 63;
  int ridx = rmap[cell];
  if (ridx < 0) { if (ln==0) { summ[cell]=0.f; cs[cell]=0.f; } return; }
  const unsigned long long* row = bits + (size_t)ridx*256;
  int cnt = 0;
  #pragma unroll
  for (int k=0;k<4;k++) cnt += __popcll(row[ln + 64*k]);
  float sp = 0.f;
  for (int i=ln; i<128; i+=64) sp += spp[(size_t)i*M_PAD + ridx];
  #pragma unroll
  for (int o=32;o>0;o>>=1) { cnt += __shfl_down(cnt,o); sp += __shfl_down(sp,o); }
  if (ln==0) {
    float smf = (float)cnt;
    float sc = scores[cell];
    float strd = (cell<1600)?4.f:(cell<2896)?8.f:(cell<3472)?16.f:(cell<3728)?32.f:64.f;
    bool keep = (smf > strd);
    float ss = sp / fmaxf(smf, 1.f);
    summ[cell] = smf;
    cs[cell] = keep ? sc*ss : 0.f;
  }
}

// ===================== K2 (fallback): original full version =====================
__global__ __launch_bounds__(256) void k2_cscore(
    const unsigned long long* __restrict__ bits, const float* __restrict__ spp,
    const float* __restrict__ scores, float* __restrict__ summ, float* __restrict__ cs,
    int nparts, int mp) {
  int cell = blockIdx.x*4 + (threadIdx.x>>6);
  int ln = threadIdx.x & 63;
  const unsigned long long* row = bits + (size_t)cell*256;
  int cnt = 0;
  #pragma unroll
  for (int k=0;k<4;k++) cnt += __popcll(row[ln + 64*k]);
  float sp = 0.f;
  for (int i=ln; i<nparts; i+=64) sp += spp[(size_t)i*mp + cell];
  #pragma unroll
  for (int o=32;o>0;o>>=1) { cnt += __shfl_down(cnt,o); sp += __shfl_down(sp,o); }
  if (ln==0) {
    float smf = (float)cnt;
    float sc = scores[cell];
    float strd = (cell<1600)?4.f:(cell<2896)?8.f:(cell<3472)?16.f:(cell<3728)?32.f:64.f;
    bool keep = (sc > 0.3f) && (smf > strd);
    float ss = sp / fmaxf(smf, 1.f);
    summ[cell] = smf;
    cs[cell] = keep ? sc*ss : 0.f;
  }
}

// ===================== K3a: bitonic sizes 2..512 on 8 parallel 512-segments =====================
__global__ __launch_bounds__(256) void k3a_sort512(const float* __restrict__ cs,
                                                   unsigned long long* __restrict__ keys) {
  __shared__ unsigned long long key[512];
  int b = blockIdx.x, tid = threadIdx.x;
  for (int i=tid;i<512;i+=256) {
    int gi = b*512 + i;
    key[i] = (gi < M_CELLS) ? packkey(cs[gi], gi) : 0ULL;
  }
  __syncthreads();
  for (int size=2; size<=512; size<<=1) {
    for (int st=size>>1; st>0; st>>=1) {
      for (int i=tid;i<512;i+=256) {
        int pp = i ^ st;
        if (pp > i) {
          unsigned long long a=key[i], bb=key[pp];
          bool desc = (((b*512+i) & size) == 0);
          if (desc ? (a<bb) : (a>bb)) { key[i]=bb; key[pp]=a; }
        }
      }
      __syncthreads();
    }
  }
  for (int i=tid;i<512;i+=256) keys[b*512+i] = key[i];
}

// ===================== K3b: bitonic sizes 1024..4096 merge + emit top500 =====================
__global__ __launch_bounds__(1024) void k3b_merge(const unsigned long long* __restrict__ keys,
    const float* __restrict__ summ,
    int* __restrict__ tidx, float* __restrict__ tsc, float* __restrict__ smt) {
  __shared__ unsigned long long key[4096];
  int tid = threadIdx.x;
  for (int i=tid;i<4096;i+=1024) key[i] = keys[i];
  __syncthreads();
  for (int size=1024; size<=4096; size<<=1) {
    for (int st=size>>1; st>0; st>>=1) {
      for (int i=tid;i<4096;i+=1024) {
        int pp = i ^ st;
        if (pp > i) {
          unsigned long long a=key[i], b=key[pp];
          bool desc = ((i & size) == 0);
          if (desc ? (a<b) : (a>b)) { key[i]=b; key[pp]=a; }
        }
      }
      __syncthreads();
    }
  }
  if (tid < 512) {
    if (tid < 500) {
      unsigned long long k = key[tid];
      int idx = (int)(0xFFFFFFFFu - (unsigned)(k & 0xFFFFFFFFull));
      tidx[tid] = idx;
      tsc[tid] = __uint_as_float((unsigned)(k>>32));
      smt[tid] = summ[idx];
    } else { tidx[tid]=0; tsc[tid]=0.f; smt[tid]=0.f; }
  }
}

// ===================== K4: pairwise mask IoU via bitset AND+popcount =====================
__global__ __launch_bounds__(256) void k4_iou(
    const unsigned long long* __restrict__ bits, const int* __restrict__ tidx,
    const int* __restrict__ rmap, const float* __restrict__ smt, float* __restrict__ iou) {
  int ti = blockIdx.y, tj = blockIdx.x;
  int tid = threadIdx.x;
  int ty = tid>>4, tx = tid&15;
  int i = ti*16+ty, j = tj*16+tx;
  if (ti > tj) { if (i<500 && j<500) iou[i*500+j] = 0.f; return; }
  __shared__ unsigned long long A[16][130];
  __shared__ unsigned long long B[16][130];
  __shared__ float sa[16], sb[16];
  if (tid<16) sa[tid] = (ti*16+tid<500) ? smt[ti*16+tid] : 0.f;
  else if (tid<32) sb[tid-16] = (tj*16+tid-16<500) ? smt[tj*16+tid-16] : 0.f;
  int inter = 0;
  for (int half=0; half<2; half++) {
    __syncthreads();
    for (int t=tid;t<2048;t+=256) {
      int r=t>>7, k=t&127;
      int ii = ti*16+r;
      int jj = tj*16+r;
      int ri = (ii<500) ? (rmap ? max(rmap[tidx[ii]],0) : tidx[ii]) : 0;
      int rj = (jj<500) ? (rmap ? max(rmap[tidx[jj]],0) : tidx[jj]) : 0;
      A[r][k] = (ii<500) ? bits[(size_t)ri*256 + half*128 + k] : 0ULL;
      B[r][k] = (jj<500) ? bits[(size_t)rj*256 + half*128 + k] : 0ULL;
    }
    __syncthreads();
    for (int k=0;k<128;k++) inter += __popcll(A[ty][k] & B[tx][k]);
  }
  if (i<500 && j<500) {
    float fi = (float)inter;
    float un = sa[ty] + sb[tx] - fi;
    iou[i*500+j] = (i<j) ? fi / fmaxf(un, 1.f) : 0.f;
  }
}

// ===================== K5: comp[j] = max_i iou[i][j] — parallel + ILP =====================
__global__ __launch_bounds__(256) void k5_comp(const float* __restrict__ iou, float* __restrict__ comp) {
  int tid = threadIdx.x;
  int tx = tid & 63, ty = tid >> 6;
  int j = blockIdx.x*64 + tx;
  float m0=0.f, m1=0.f, m2=0.f, m3=0.f;
  if (j < 500) {
    int i = ty;
    for (; i+12 < 500; i += 16) {
      m0 = fmaxf(m0, iou[(i   )*500 + j]);
      m1 = fmaxf(m1, iou[(i+ 4)*500 + j]);
      m2 = fmaxf(m2, iou[(i+ 8)*500 + j]);
      m3 = fmaxf(m3, iou[(i+12)*500 + j]);
    }
    for (; i < 500; i += 4) m0 = fmaxf(m0, iou[i*500 + j]);
  }
  float m = fmaxf(fmaxf(m0,m1), fmaxf(m2,m3));
  __shared__ float red[4][64];
  red[ty][tx] = m;
  __syncthreads();
  if (ty == 0 && j < 512)
    comp[j] = (j < 500) ? fmaxf(fmaxf(red[0][tx],red[1][tx]), fmaxf(red[2][tx],red[3][tx])) : 0.f;
}

// ===================== K6: decay + threshold — parallel + ILP =====================
__global__ __launch_bounds__(256) void k6_decay(
    const float* __restrict__ iou, const float* __restrict__ comp,
    const float* __restrict__ tsc, float* __restrict__ nms) {
  __shared__ float csh[512];
  int tid = threadIdx.x;
  for (int i=tid; i<512; i+=256) csh[i] = (i<500) ? comp[i] : 0.f;
  __syncthreads();
  int tx = tid & 63, ty = tid >> 6;
  int j = blockIdx.x*64 + tx;
  float t0=-1e30f, t1=-1e30f, t2=-1e30f, t3=-1e30f;
  if (j < 500) {
    int i = ty;
    for (; i+12 < 500; i += 16) {
      float v0 = iou[(i   )*500 + j], c0 = csh[i];
      float v1 = iou[(i+ 4)*500 + j], c1 = csh[i+4];
      float v2 = iou[(i+ 8)*500 + j], c2 = csh[i+8];
      float v3 = iou[(i+12)*500 + j], c3 = csh[i+12];
      t0 = fmaxf(t0, v0*v0 - c0*c0);
      t1 = fmaxf(t1, v1*v1 - c1*c1);
      t2 = fmaxf(t2, v2*v2 - c2*c2);
      t3 = fmaxf(t3, v3*v3 - c3*c3);
    }
    for (; i < 500; i += 4) { float v = iou[i*500 + j]; float c = csh[i]; t0 = fmaxf(t0, v*v - c*c); }
  }
  float t = fmaxf(fmaxf(t0,t1), fmaxf(t2,t3));
  __shared__ float red[4][64];
  red[ty][tx] = t;
  __syncthreads();
  if (ty == 0 && j < 512) {
    float out = 0.f;
    if (j < 500) {
      float tt = fmaxf(fmaxf(red[0][tx],red[1][tx]), fmaxf(red[2][tx],red[3][tx]));
      float s = tsc[j] * __expf(-2.f*tt);
      out = (s >= 0.05f) ? s : 0.f;
    }
    nms[j] = out;
  }
}

// ===================== K7: top-30 (+ fused Af30 pack when kfT != null) =====================
__global__ __launch_bounds__(256) void k7_top30(
    const float* __restrict__ nms, const int* __restrict__ tidx,
    int* __restrict__ sel, float* __restrict__ out,
    const float* __restrict__ kfT, _Float16* __restrict__ Af30) {
  __shared__ unsigned long long key[512];
  __shared__ int selsh[30];
  int tid = threadIdx.x;
  for (int i=tid;i<512;i+=256) key[i] = (i<500) ? packkey(nms[i], i) : 0ULL;
  __syncthreads();
  for (int size=2; size<=512; size<<=1) {
    for (int st=size>>1; st>0; st>>=1) {
      for (int i=tid;i<512;i+=256) {
        int pp = i ^ st;
        if (pp > i) {
          unsigned long long a=key[i], b=key[pp];
          bool desc = ((i & size) == 0);
          if (desc ? (a<b) : (a>b)) { key[i]=b; key[pp]=a; }
        }
      }
      __syncthreads();
    }
  }
  if (tid < 30) {
    unsigned long long k = key[tid];
    int j = (int)(0xFFFFFFFFu - (unsigned)(k & 0xFFFFFFFFull));
    float v = __uint_as_float((unsigned)(k>>32));
    out[120+tid] = v;
    out[150+tid] = (v > 0.3f) ? 1.f : 0.f;
    sel[tid] = tidx[j];
    selsh[tid] = tidx[j];
  }
  __syncthreads();
  if (kfT) {
    for (int P = tid; P < 1024; P += 256) {
      int sub = P >> 7, pc = P & 127;
      int ks = sub >> 1, h = sub & 1;
      int mn = pc >> 6, ln = pc & 63;
      int m  = mn*16 + (ln & 15);
      int kb = ks*32 + (ln >> 4)*8;
      half8 o;
      if (m < 30) {
        const float* src = kfT + selsh[m];
        #pragma unroll
        for (int j=0;j<8;j++) {
          float x = src[(size_t)(kb+j)*M_PAD];
          _Float16 hi = (_Float16)x;
          o[j] = h ? (_Float16)(x - (float)hi) : hi;
        }
      } else {
        #pragma unroll
        for (int j=0;j<8;j++) o[j] = (_Float16)0.f;
      }
      *(half8*)&Af30[(size_t)P*8] = o;
    }
  }
}

// ===================== K8 (MFMA): 32x16384x128 GEMM -> selp probs =====================
__global__ __launch_bounds__(256) void k8_mfma(const _Float16* __restrict__ Af30,
                                               const _Float16* __restrict__ Bf,
                                               float* __restrict__ selp) {
  const int nb = blockIdx.x;
  const int lane = threadIdx.x & 63;
  const int w = threadIdx.x >> 6;
  const half8* A = (const half8*)Af30;                    // [sub][128]
  const half8* B = (const half8*)Bf + (size_t)nb*4096;    // [sub][512]
  f32x4 acc[2][2];
  #pragma unroll
  for (int a=0;a<2;a++)
    #pragma unroll
    for (int b=0;b<2;b++) acc[a][b] = (f32x4){0.f,0.f,0.f,0.f};
  #pragma unroll
  for (int ks=0; ks<4; ks++) {
    half8 ah[2], bh[2], al[2], bl[2];
    #pragma unroll
    for (int mt=0; mt<2; mt++) ah[mt] = A[(ks*2+0)*128 + mt*64 + lane];
    #pragma unroll
    for (int nt=0; nt<2; nt++) bh[nt] = B[(size_t)(ks*2+0)*512 + (w*2+nt)*64 + lane];
    #pragma unroll
    for (int mt=0; mt<2; mt++) al[mt] = A[(ks*2+1)*128 + mt*64 + lane];
    #pragma unroll
    for (int nt=0; nt<2; nt++) bl[nt] = B[(size_t)(ks*2+1)*512 + (w*2+nt)*64 + lane];
    #pragma unroll
    for (int nt=0; nt<2; nt++)
      #pragma unroll
      for (int mt=0; mt<2; mt++) {
        acc[mt][nt] = __builtin_amdgcn_mfma_f32_16x16x32_f16(ah[mt], bh[nt], acc[mt][nt], 0, 0, 0);
        acc[mt][nt] = __builtin_amdgcn_mfma_f32_16x16x32_f16(ah[mt], bl[nt], acc[mt][nt], 0, 0, 0);
        acc[mt][nt] = __builtin_amdgcn_mfma_f32_16x16x32_f16(al[mt], bh[nt], acc[mt][nt], 0, 0, 0);
      }
  }
  const int q = lane >> 4, col = lane & 15;
  #pragma unroll
  for (int mt=0; mt<2; mt++)
    #pragma unroll
    for (int nt=0; nt<2; nt++)
      #pragma unroll
      for (int reg=0; reg<4; reg++) {
        int m = mt*16 + q*4 + reg;
        if (m < 30) {
          int px = nb*128 + w*32 + nt*16 + col;
          float lg = acc[mt][nt][reg];
          selp[(size_t)m*NPIX + px] = __fdividef(1.f, 1.f + __expf(-lg));
        }
      }
}

// ===================== K8 (fallback): probs for 30 selected masks =====================
__global__ __launch_bounds__(256) void k8_selp(
    const float* __restrict__ kf, const float* __restrict__ seg,
    const int* __restrict__ sel, float* __restrict__ selp) {
  int px = blockIdx.x*256 + threadIdx.x;
  int cells[30];
  #pragma unroll
  for (int m=0;m<30;m++) cells[m] = __builtin_amdgcn_readfirstlane(sel[m]);
  float acc[30];
  #pragma unroll
  for (int m=0;m<30;m++) acc[m] = 0.f;
  for (int e=0; e<128; e+=4) {
    float s0 = seg[(size_t)(e+0)*NPIX + px];
    float s1 = seg[(size_t)(e+1)*NPIX + px];
    float s2 = seg[(size_t)(e+2)*NPIX + px];
    float s3 = seg[(size_t)(e+3)*NPIX + px];
    #pragma unroll
    for (int m=0;m<30;m++) {
      const float* kr = kf + (size_t)cells[m]*128 + e;
      acc[m] = fmaf(kr[0], s0, fmaf(kr[1], s1, fmaf(kr[2], s2, fmaf(kr[3], s3, acc[m]))));
    }
  }
  #pragma unroll
  for (int m=0;m<30;m++)
    selp[(size_t)m*NPIX + px] = __fdividef(1.f, 1.f + __expf(-acc[m]));
}

// ===================== K9a: per-(mask,row) upsample -> per-row min/max (round-11 version) ======
__global__ __launch_bounds__(256) void k9a_rows(const float* __restrict__ selp,
                                               int* __restrict__ rowmn, int* __restrict__ rowmx) {
  int msk = blockIdx.y, oy = blockIdx.x;
  const float* mp = selp + (size_t)msk*NPIX;
  __shared__ float rows[2][128];
  __shared__ int wmn[4], wmx[4];
  int tid = threadIdx.x;
  float yf = fminf(fmaxf((oy+0.5f)*0.25f - 0.5f, 0.f), 127.f);
  int y0 = (int)yf, y1 = min(y0+1,127);
  float fy = yf-(float)y0;
  if (tid < 128) rows[0][tid] = mp[y0*128 + tid];
  else           rows[1][tid-128] = mp[y1*128 + tid-128];
  __syncthreads();
  int mnx = 512, mxx = -1;
  #pragma unroll
  for (int h=0; h<2; h++) {
    int ox = tid + h*256;
    float xf = fminf(fmaxf((ox+0.5f)*0.25f - 0.5f, 0.f), 127.f);
    int x0 = (int)xf, x1 = min(x0+1,127);
    float fx = xf-(float)x0;
    float v0 = rows[0][x0]*(1.f-fx) + rows[0][x1]*fx;
    float v1 = rows[1][x0]*(1.f-fx) + rows[1][x1]*fx;
    float v  = v0*(1.f-fy) + v1*fy;
    if (v > 0.5f) { mnx = min(mnx, ox); mxx = max(mxx, ox); }
  }
  #pragma unroll
  for (int o=32;o>0;o>>=1) {
    mnx = min(mnx, __shfl_down(mnx, o));
    mxx = max(mxx, __shfl_down(mxx, o));
  }
  if ((tid & 63) == 0) { wmn[tid>>6] = mnx; wmx[tid>>6] = mxx; }
  __syncthreads();
  if (tid == 0) {
    rowmn[msk*512 + oy] = min(min(wmn[0],wmn[1]), min(wmn[2],wmn[3]));
    rowmx[msk*512 + oy] = max(max(wmx[0],wmx[1]), max(wmx[2],wmx[3]));
  }
}

// ===================== K9b: per-row results -> bbox (LDS tree reduce) =====================
__global__ __launch_bounds__(512) void k9b_box(const int* __restrict__ rowmn,
                                              const int* __restrict__ rowmx, float* out) {
  int msk = blockIdx.x, tid = threadIdx.x;
  __shared__ int r0[512], r1[512], r2[512], r3[512];
  int mn = rowmn[msk*512 + tid];
  int mx = rowmx[msk*512 + tid];
  bool occ = (mx >= 0);
  r0[tid] = mn;
  r1[tid] = mx;
  r2[tid] = occ ? tid : 512;
  r3[tid] = occ ? tid : -1;
  __syncthreads();
  for (int s=256;s>0;s>>=1) {
    if (tid<s) {
      r0[tid]=min(r0[tid],r0[tid+s]); r1[tid]=max(r1[tid],r1[tid+s]);
      r2[tid]=min(r2[tid],r2[tid+s]); r3[tid]=max(r3[tid],r3[tid+s]);
    }
    __syncthreads();
  }
  if (tid==0) {
    bool vis = out[120+msk] > 0.3f;
    out[msk*4+0] = vis ? (float)r0[0] : 0.f;   // xmin (512 if empty, matches ref)
    out[msk*4+1] = vis ? (float)r2[0] : 0.f;   // ymin
    out[msk*4+2] = vis ? (float)r1[0] : 0.f;   // xmax (-1 if empty)
    out[msk*4+3] = vis ? (float)r3[0] : 0.f;   // ymax
  }
}

// ===================== launch =====================
extern "C" void kernel_launch(void* const* d_in, const int* in_sizes, int n_in,
                              void* d_out, int out_size, void* d_ws, size_t ws_size,
                              hipStream_t stream) {
  (void)in_sizes; (void)n_in; (void)out_size;
  if (ws_size < WS_FB) return;
  const float* cate[5]; const float* kern[5];
  for (int i=0;i<5;i++){ cate[i]=(const float*)d_in[2*i]; kern[i]=(const float*)d_in[2*i+1]; }
  const float* seg = (const float*)d_in[10];
  char* ws = (char*)d_ws;
  float* out = (float*)d_out;

  const bool mfma = (ws_size >= WS_MFMA);

  float* kf      = (float*)(ws + (mfma ? B_KF   : F_KF));   // MFMA path: kfT e-major
  float* scores  = (float*)(ws + (mfma ? B_SC   : F_SC));
  float* summ    = (float*)(ws + (mfma ? B_SM   : F_SM));
  float* cs      = (float*)(ws + (mfma ? B_CS   : F_CS));
  unsigned long long* bits = (unsigned long long*)(ws + (mfma ? B_BIT : F_BIT));
  float* spp     = (float*)(ws + (mfma ? B_SPP  : F_SPP));
  int*   tidx    = (int*)(ws + (mfma ? B_TIDX : F_TIDX));
  float* tsc     = (float*)(ws + (mfma ? B_TSC  : F_TSC));
  float* smt     = (float*)(ws + (mfma ? B_SMT  : F_SMT));
  float* iou     = (float*)(ws + (mfma ? B_IOU  : F_IOU));
  float* comp    = (float*)(ws + (mfma ? B_COMP : F_COMP));
  float* nms     = (float*)(ws + (mfma ? B_NMS  : F_NMS));
  int*   sel     = (int*)(ws + (mfma ? B_SEL  : F_SEL));
  float* selp    = (float*)(ws + (mfma ? B_SELP : F_SELP));
  int*   rowmn   = (int*)(ws + (mfma ? B_RMN  : F_RMN));
  int*   rowmx   = (int*)(ws + (mfma ? B_RMX  : F_RMX));
  unsigned long long* keys = (unsigned long long*)(ws + (mfma ? B_KEYS : F_KEYS));

  if (mfma) {
    _Float16* Af = (_Float16*)(ws + B_AFR);
    _Float16* Bf = (_Float16*)(ws + B_BFR);
    _Float16* Af30 = (_Float16*)(ws + B_AF30);
    int* cmap = (int*)(ws + B_CMAP);
    int* rmap = (int*)(ws + B_RMAP);
    int* vcnt = (int*)(ws + B_VCNT);
    hipMemsetAsync(vcnt, 0, 4, stream);
    k0_fused <<<6048, 256, 0, stream>>>(cate[0],cate[1],cate[2],cate[3],cate[4],
                                      kern[0],kern[1],kern[2],kern[3],kern[4], seg,
                                      kf, scores, cmap, rmap, vcnt, Bf);
    k0b_afrag<<<31*4096/256, 256, 0, stream>>>(kf, cmap, vcnt, Af);
    k1_mfma  <<<dim3(31, 128), 256, 0, stream>>>(Af, Bf, vcnt, bits, spp);
    k2c_cscore<<<M_CELLS/4, 256, 0, stream>>>(bits, spp, scores, rmap, summ, cs);
    k3a_sort512<<<8, 256, 0, stream>>>(cs, keys);
    k3b_merge  <<<1, 1024, 0, stream>>>(keys, summ, tidx, tsc, smt);
    k4_iou   <<<dim3(32,32), 256, 0, stream>>>(bits, tidx, rmap, smt, iou);
    k5_comp  <<<8, 256, 0, stream>>>(iou, comp);
    k6_decay <<<8, 256, 0, stream>>>(iou, comp, tsc, nms);
    k7_top30 <<<1, 256, 0, stream>>>(nms, tidx, sel, out, kf, Af30);
    k8_mfma  <<<128, 256, 0, stream>>>(Af30, Bf, selp);
  } else {
    k0a_gather<<<dim3(800,5), 256, 0, stream>>>(cate[0],cate[1],cate[2],cate[3],cate[4],
                                      kern[0],kern[1],kern[2],kern[3],kern[4], kf, scores);
    k1_gemm  <<<dim3(64,121), 256, 0, stream>>>(kf, seg, bits, spp);
    k2_cscore<<<M_CELLS/4, 256, 0, stream>>>(bits, spp, scores, summ, cs, 64, M_CELLS);
    k3a_sort512<<<8, 256, 0, stream>>>(cs, keys);
    k3b_merge  <<<1, 1024, 0, stream>>>(keys, summ, tidx, tsc, smt);
    k4_iou   <<<dim3(32,32), 256, 0, stream>>>(bits, tidx, nullptr, smt, iou);
    k5_comp  <<<8, 256, 0, stream>>>(iou, comp);
    k6_decay <<<8, 256, 0, stream>>>(iou, comp, tsc, nms);
    k7_top30 <<<1, 256, 0, stream>>>(nms, tidx, sel, out, nullptr, nullptr);
    k8_selp  <<<NPIX/256, 256, 0, stream>>>(kf, seg, sel, selp);
  }
  k9a_rows <<<dim3(512,30), 256, 0, stream>>>(selp, rowmn, rowmx);
  k9b_box  <<<30, 512, 0, stream>>>(rowmn, rowmx, out);
}

// Round 15
// 277.727 us; speedup vs baseline: 1.5647x; 1.0203x over previous
//
#include <hip/hip_runtime.h>
#include <math.h>

#define M_CELLS 3872
#define M_PAD   3968   // 31 * 128
#define NPIX    16384  // 128*128

typedef _Float16 half8 __attribute__((ext_vector_type(8)));
typedef float f32x4 __attribute__((ext_vector_type(4)));

// async global->LDS 16B: per-lane global addr, wave-uniform LDS base (+lane*16 in HW)
#define GL2LDS(g, l) __builtin_amdgcn_global_load_lds( \
    (const __attribute__((address_space(1))) unsigned int*)(g), \
    (__attribute__((address_space(3))) unsigned int*)(l), 16, 0, 0)

// NOTE (round 12): cg::grid.sync() costs ~25-30 µs on gfx950 (device-scope coherence across
// 8 non-coherent per-XCD L2s). Kernel-boundary deps are CHEAPER than in-kernel grid sync.
// NOTE (round 13): k9a 8-rows-per-block variant regressed ~12 µs vs per-row blocks; reverted.
// NOTE (round 14): fusing k0aT+k0c into one dispatch cost ~5 µs (gather blocks queue behind
// B-frag blocks, delaying k0b's dependency); separate dispatches are faster. Reverted.

// ===================== workspace layouts =====================
static constexpr size_t ALN(size_t x){ return (x + 255) & ~(size_t)255; }

// ---- fallback layout ----
static constexpr size_t F_KF   = 0;
static constexpr size_t F_SC   = F_KF + (size_t)M_CELLS*128*4;
static constexpr size_t F_SM   = F_SC + (size_t)M_CELLS*4;
static constexpr size_t F_CS   = F_SM + (size_t)M_CELLS*4;
static constexpr size_t F_BIT  = F_CS + (size_t)M_CELLS*4;
static constexpr size_t F_SPP  = F_BIT + (size_t)M_CELLS*256*8;
static constexpr size_t F_TIDX = F_SPP + (size_t)64*M_CELLS*4;
static constexpr size_t F_TSC  = F_TIDX + 512*4;
static constexpr size_t F_SMT  = F_TSC + 512*4;
static constexpr size_t F_IOU  = F_SMT + 512*4;
static constexpr size_t F_COMP = F_IOU + (size_t)500*500*4;
static constexpr size_t F_NMS  = F_COMP + 512*4;
static constexpr size_t F_SEL  = F_NMS + 512*4;
static constexpr size_t F_SELP = F_SEL + 32*4;
static constexpr size_t F_RMN  = ALN(F_SELP + (size_t)30*NPIX*4);   // int[30*512] per-row min-x
static constexpr size_t F_RMX  = F_RMN + 30*512*4;                  // int[30*512] per-row max-x
static constexpr size_t F_KEYS = ALN(F_RMX + 30*512*4);
static constexpr size_t WS_FB  = F_KEYS + 4096*8;

// ---- MFMA layout (~25 MB, proven to fit in rounds 2-14) ----
static constexpr size_t B_KF   = 0;                                       // float kfT[128][M_PAD] e-major
static constexpr size_t B_AFR  = ALN(B_KF  + (size_t)M_PAD*128*4);        // frag A: [31][8 sub][512 pc][16B] = 2MB
static constexpr size_t B_BFR  = ALN(B_AFR + (size_t)31*4096*16);         // frag B: [128][8 sub][512 pc][16B] = 8MB
static constexpr size_t B_SC   = ALN(B_BFR + (size_t)128*4096*16);
static constexpr size_t B_SM   = ALN(B_SC + (size_t)M_PAD*4);
static constexpr size_t B_CS   = ALN(B_SM + (size_t)M_PAD*4);
static constexpr size_t B_BIT  = ALN(B_CS + (size_t)M_PAD*4);
static constexpr size_t B_SPP  = ALN(B_BIT + (size_t)M_PAD*256*8);
static constexpr size_t B_TIDX = ALN(B_SPP + (size_t)128*M_PAD*4);
static constexpr size_t B_TSC  = ALN(B_TIDX + 512*4);
static constexpr size_t B_SMT  = ALN(B_TSC + 512*4);
static constexpr size_t B_IOU  = ALN(B_SMT + 512*4);
static constexpr size_t B_COMP = ALN(B_IOU + (size_t)500*500*4);
static constexpr size_t B_NMS  = ALN(B_COMP + 512*4);
static constexpr size_t B_SEL  = ALN(B_NMS + 512*4);
static constexpr size_t B_SELP = ALN(B_SEL + 32*4);
static constexpr size_t B_RMN  = ALN(B_SELP + (size_t)30*NPIX*4);
static constexpr size_t B_RMX  = B_RMN + 30*512*4;
static constexpr size_t B_CMAP = ALN(B_RMX + 30*512*4);   // int[4096] newIdx -> cell
static constexpr size_t B_RMAP = B_CMAP + 4096*4;         // int[4096] cell -> newIdx | -1
static constexpr size_t B_VCNT = B_RMAP + 4096*4;         // int[64]
static constexpr size_t B_KEYS = ALN(B_VCNT + 64*4);      // u64[4096]
static constexpr size_t B_AF30 = ALN(B_KEYS + 4096*8);    // frag A30: [8 sub][128 pc][16B] = 16KB
static constexpr size_t WS_MFMA = B_AF30 + 8*128*16;

__device__ inline unsigned long long packkey(float v, int i) {
  return ((unsigned long long)__float_as_uint(v) << 32) | (unsigned)(0xFFFFFFFFu - (unsigned)i);
}

// ===================== K0aT (MFMA): gather kernels e-major + scores + inline compaction =====================
__global__ __launch_bounds__(256) void k0aT_gather(
    const float* __restrict__ c0,const float* __restrict__ c1,const float* __restrict__ c2,
    const float* __restrict__ c3,const float* __restrict__ c4,
    const float* __restrict__ w0,const float* __restrict__ w1,const float* __restrict__ w2,
    const float* __restrict__ w3,const float* __restrict__ w4,
    float* __restrict__ kfT, float* __restrict__ scores,
    int* __restrict__ cmap, int* __restrict__ rmap, int* __restrict__ vcnt) {
  const int lvl = blockIdx.y;
  const int Gs[5]   = {1600,1296,576,256,144};
  const int offs[5] = {0,1600,2896,3472,3728};
  const int G = Gs[lvl], off = offs[lvl];
  const float* kl = (lvl==0)?w0:(lvl==1)?w1:(lvl==2)?w2:(lvl==3)?w3:w4;
  const float* cl = (lvl==0)?c0:(lvl==1)?c1:(lvl==2)?c2:(lvl==3)?c3:c4;
  int t = blockIdx.x*256 + threadIdx.x;
  if (t >= G*128) return;
  int e = t / G, c = t - e*G;
  kfT[(size_t)e*M_PAD + off + c] = kl[t];
  if (e == 0) {
    int cell = off + c;
    float sc = cl[c];
    scores[cell] = sc;
    if (sc > 0.3f) {
      int run = atomicAdd(vcnt, 1);
      cmap[run] = cell;
      rmap[cell] = run;
    } else rmap[cell] = -1;
  }
}

// ===================== K0a (fallback): row-major kf =====================
__global__ __launch_bounds__(256) void k0a_gather(
    const float* __restrict__ c0,const float* __restrict__ c1,const float* __restrict__ c2,
    const float* __restrict__ c3,const float* __restrict__ c4,
    const float* __restrict__ w0,const float* __restrict__ w1,const float* __restrict__ w2,
    const float* __restrict__ w3,const float* __restrict__ w4,
    float* __restrict__ kf, float* __restrict__ scores) {
  const int lvl = blockIdx.y;
  const int Gs[5]   = {1600,1296,576,256,144};
  const int offs[5] = {0,1600,2896,3472,3728};
  const int G = Gs[lvl], off = offs[lvl];
  const float* kl = (lvl==0)?w0:(lvl==1)?w1:(lvl==2)?w2:(lvl==3)?w3:w4;
  const float* cl = (lvl==0)?c0:(lvl==1)?c1:(lvl==2)?c2:(lvl==3)?c3:c4;
  int t = blockIdx.x*256 + threadIdx.x;
  if (t >= G*128) return;
  int e = t / G, c = t - e*G;
  kf[(size_t)(off+c)*128 + e] = kl[t];
  if (e == 0) scores[off+c] = cl[c];
}

// ===================== K0b: kfT -> frag-ordered A (compacted rows) =====================
__global__ __launch_bounds__(256) void k0b_afrag(const float* __restrict__ kfT,
                                                 const int* __restrict__ cmap,
                                                 const int* __restrict__ vcnt,
                                                 _Float16* __restrict__ Af) {
  int P = blockIdx.x*256 + threadIdx.x;     // 31*4096 = 126976
  int mblock = P >> 12;
  int r  = P & 4095;
  int sub = r >> 9, pc = r & 511;
  int ks = sub >> 1, h = sub & 1;
  int mn = pc >> 6, ln = pc & 63;
  int mcomp = mblock*128 + mn*16 + (ln & 15);
  int kb = ks*32 + (ln >> 4)*8;
  half8 o;
  if (mcomp < vcnt[0]) {
    const float* src = kfT + cmap[mcomp];
    #pragma unroll
    for (int j=0;j<8;j++) {
      float x = src[(size_t)(kb+j)*M_PAD];
      _Float16 hi = (_Float16)x;
      o[j] = h ? (_Float16)(x - (float)hi) : hi;
    }
  } else {
    #pragma unroll
    for (int j=0;j<8;j++) o[j] = (_Float16)0.f;
  }
  *(half8*)&Af[(size_t)P*8] = o;
}

// ===================== K0c: seg -> frag-ordered B =====================
__global__ __launch_bounds__(256) void k0c_bfrag(const float* __restrict__ seg,
                                                 _Float16* __restrict__ Bf) {
  int P = blockIdx.x*256 + threadIdx.x;     // 128*4096 = 524288
  int nb = P >> 12;
  int r  = P & 4095;
  int sub = r >> 9, pc = r & 511;
  int ks = sub >> 1, h = sub & 1;
  int mn = pc >> 6, ln = pc & 63;
  int px = nb*128 + mn*16 + (ln & 15);
  int kb = ks*32 + (ln >> 4)*8;
  half8 o;
  #pragma unroll
  for (int j=0;j<8;j++) {
    float x = seg[(size_t)(kb+j)*NPIX + px];
    _Float16 hi = (_Float16)x;
    o[j] = h ? (_Float16)(x - (float)hi) : hi;
  }
  *(half8*)&Bf[(size_t)P*8] = o;
}

// ===================== K1 (fallback): fp32 vector GEMM =====================
__global__ __launch_bounds__(256, 6) void k1_gemm(
    const float* __restrict__ kf, const float* __restrict__ seg,
    unsigned long long* __restrict__ bits, float* __restrict__ spp) {
  int tid = threadIdx.x;
  int p  = blockIdx.x*256 + tid;
  int c0 = blockIdx.y*32;
  float acc[32];
  #pragma unroll
  for (int c=0;c<32;c++) acc[c]=0.f;
  for (int ch=0; ch<8; ch++) {
    float s[16];
    #pragma unroll
    for (int e=0;e<16;e++) s[e] = seg[(size_t)(ch*16+e)*NPIX + p];
    #pragma unroll
    for (int c=0;c<32;c++) {
      float a=0.f;
      #pragma unroll
      for (int e=0;e<16;e++) a = fmaf(kf[(size_t)(c0+c)*128 + ch*16 + e], s[e], a);
      acc[c] += a;
    }
  }
  int wv = tid>>6, ln = tid&63;
  __shared__ float wsum[32][4];
  #pragma unroll
  for (int c=0;c<32;c++) {
    float logit = acc[c];
    bool msk = logit > 0.f;
    unsigned long long bal = __ballot(msk);
    float pr = msk ? __fdividef(1.f, 1.f + __expf(-logit)) : 0.f;
    #pragma unroll
    for (int o=32;o>0;o>>=1) pr += __shfl_down(pr, o);
    if (ln==0) {
      bits[(size_t)(c0+c)*256 + blockIdx.x*4 + wv] = bal;
      wsum[c][wv] = pr;
    }
  }
  __syncthreads();
  if (tid < 32)
    spp[(size_t)blockIdx.x*M_CELLS + c0 + tid] = wsum[tid][0]+wsum[tid][1]+wsum[tid][2]+wsum[tid][3];
}

// ===================== K1 (MFMA): compacted rows; 16KB sub-steps, dbuf, (256,4) =====================
// NOTE: (256,5) forced VGPR 64->48 and spilled acc to scratch (431MB HBM writes, 2.2x slower).
// (256,4) keeps VGPR=64, no spill — measured 58-60 µs. Do not raise min-waves here.
__global__ __launch_bounds__(256, 4) void k1_mfma(
    const _Float16* __restrict__ Af, const _Float16* __restrict__ Bf,
    const int* __restrict__ vcnt,
    unsigned long long* __restrict__ bits, float* __restrict__ spp) {
  if (blockIdx.x*128 >= vcnt[0]) return;   // compacted tail: no valid rows
  __shared__ char lds[32768];   // 2 x (A 8KB | B 8KB)
  const int tid  = threadIdx.x;
  const int lane = tid & 63;
  const int wave = tid >> 6;
  const int wr = wave >> 1, wc = wave & 1;
  const char* gA = (const char*)Af + (size_t)blockIdx.x*65536;
  const char* gB = (const char*)Bf + (size_t)blockIdx.y*65536;

  f32x4 acc[4][4];
  #pragma unroll
  for (int a=0;a<4;a++)
    #pragma unroll
    for (int b=0;b<4;b++) acc[a][b] = (f32x4){0.f,0.f,0.f,0.f};

  auto issue = [&](int sub, int buf) {
    const char* ga = gA + sub*8192;
    const char* gb = gB + sub*8192;
    char* la = &lds[buf*16384];
    char* lb = &lds[buf*16384 + 8192];
    GL2LDS(ga +  wave   *1024 + lane*16, la +  wave   *1024);
    GL2LDS(ga + (wave+4)*1024 + lane*16, la + (wave+4)*1024);
    GL2LDS(gb +  wave   *1024 + lane*16, lb +  wave   *1024);
    GL2LDS(gb + (wave+4)*1024 + lane*16, lb + (wave+4)*1024);
  };

  issue(0, 0);
  half8 ah[4], bh[4];
  #pragma unroll
  for (int s=0; s<8; s++) {
    __syncthreads();
    if (s < 7) issue(s+1, (s+1)&1);
    const char* lb_ = &lds[(s&1)*16384];
    if ((s & 1) == 0) {
      #pragma unroll
      for (int mt=0; mt<4; mt++) ah[mt] = *(const half8*)&lb_[(wr*4+mt)*1024 + lane*16];
      #pragma unroll
      for (int nt=0; nt<4; nt++) bh[nt] = *(const half8*)&lb_[8192 + (wc*4+nt)*1024 + lane*16];
      #pragma unroll
      for (int nt=0; nt<4; nt++)
        #pragma unroll
        for (int mt=0; mt<4; mt++)
          acc[mt][nt] = __builtin_amdgcn_mfma_f32_16x16x32_f16(ah[mt], bh[nt], acc[mt][nt], 0, 0, 0);
    } else {
      #pragma unroll
      for (int nt=0; nt<4; nt++) {
        half8 bl = *(const half8*)&lb_[8192 + (wc*4+nt)*1024 + lane*16];
        #pragma unroll
        for (int mt=0; mt<4; mt++)
          acc[mt][nt] = __builtin_amdgcn_mfma_f32_16x16x32_f16(ah[mt], bl, acc[mt][nt], 0, 0, 0);
      }
      #pragma unroll
      for (int mt=0; mt<4; mt++) {
        half8 al = *(const half8*)&lb_[(wr*4+mt)*1024 + lane*16];
        #pragma unroll
        for (int nt=0; nt<4; nt++)
          acc[mt][nt] = __builtin_amdgcn_mfma_f32_16x16x32_f16(al, bh[nt], acc[mt][nt], 0, 0, 0);
      }
    }
  }
  __syncthreads();

  const int q = lane >> 4, mm = lane & 15;
  const int mbase = blockIdx.x * 128;
  const int wordIdx = blockIdx.y*2 + wc;
  float* ldsf = (float*)lds;
  #pragma unroll
  for (int mt=0; mt<4; mt++) {
    #pragma unroll
    for (int reg=0; reg<4; reg++) {
      unsigned long long bal[4];
      float ps = 0.f;
      #pragma unroll
      for (int nt=0; nt<4; nt++) {
        float lg = acc[mt][nt][reg];
        bal[nt] = __ballot(lg > 0.f);
        if (lg > 0.f) ps += __fdividef(1.f, 1.f + __expf(-lg));
      }
      ps += __shfl_xor(ps, 1); ps += __shfl_xor(ps, 2);
      ps += __shfl_xor(ps, 4); ps += __shfl_xor(ps, 8);
      if (mm == 0) {
        int cl = wr*64 + mt*16 + q*4 + reg;
        unsigned long long wd = 0;
        #pragma unroll
        for (int nt=0; nt<4; nt++)
          wd |= ((bal[nt] >> (q*16)) & 0xFFFFull) << (nt*16);
        bits[(size_t)(mbase + cl)*256 + wordIdx] = wd;
        ldsf[cl*2 + wc] = ps;
      }
    }
  }
  __syncthreads();
  if (tid < 128)
    spp[(size_t)blockIdx.y*M_PAD + mbase + tid] = ldsf[tid*2] + ldsf[tid*2+1];
}

// ===================== K2 (compact): sum_masks + seg_score + cscore via rmap =====================
__global__ __launch_bounds__(256) void k2c_cscore(
    const unsigned long long* __restrict__ bits, const float* __restrict__ spp,
    const float* __restrict__ scores, const int* __restrict__ rmap,
    float* __restrict__ summ, float* __restrict__ cs) {
  int cell = blockIdx.x*4 + (threadIdx.x>>6);
  int ln = threadIdx.x & 63;
  int ridx = rmap[cell];
  if (ridx < 0) { if (ln==0) { summ[cell]=0.f; cs[cell]=0.f; } return; }
  const unsigned long long* row = bits + (size_t)ridx*256;
  int cnt = 0;
  #pragma unroll
  for (int k=0;k<4;k++) cnt += __popcll(row[ln + 64*k]);
  float sp = 0.f;
  for (int i=ln; i<128; i+=64) sp += spp[(size_t)i*M_PAD + ridx];
  #pragma unroll
  for (int o=32;o>0;o>>=1) { cnt += __shfl_down(cnt,o); sp += __shfl_down(sp,o); }
  if (ln==0) {
    float smf = (float)cnt;
    float sc = scores[cell];
    float strd = (cell<1600)?4.f:(cell<2896)?8.f:(cell<3472)?16.f:(cell<3728)?32.f:64.f;
    bool keep = (smf > strd);
    float ss = sp / fmaxf(smf, 1.f);
    summ[cell] = smf;
    cs[cell] = keep ? sc*ss : 0.f;
  }
}

// ===================== K2 (fallback): original full version =====================
__global__ __launch_bounds__(256) void k2_cscore(
    const unsigned long long* __restrict__ bits, const float* __restrict__ spp,
    const float* __restrict__ scores, float* __restrict__ summ, float* __restrict__ cs,
    int nparts, int mp) {
  int cell = blockIdx.x*4 + (threadIdx.x>>6);
  int ln = threadIdx.x & 63;
  const unsigned long long* row = bits + (size_t)cell*256;
  int cnt = 0;
  #pragma unroll
  for (int k=0;k<4;k++) cnt += __popcll(row[ln + 64*k]);
  float sp = 0.f;
  for (int i=ln; i<nparts; i+=64) sp += spp[(size_t)i*mp + cell];
  #pragma unroll
  for (int o=32;o>0;o>>=1) { cnt += __shfl_down(cnt,o); sp += __shfl_down(sp,o); }
  if (ln==0) {
    float smf = (float)cnt;
    float sc = scores[cell];
    float strd = (cell<1600)?4.f:(cell<2896)?8.f:(cell<3472)?16.f:(cell<3728)?32.f:64.f;
    bool keep = (sc > 0.3f) && (smf > strd);
    float ss = sp / fmaxf(smf, 1.f);
    summ[cell] = smf;
    cs[cell] = keep ? sc*ss : 0.f;
  }
}

// ===================== K3a: bitonic sizes 2..512 on 8 parallel 512-segments =====================
__global__ __launch_bounds__(256) void k3a_sort512(const float* __restrict__ cs,
                                                   unsigned long long* __restrict__ keys) {
  __shared__ unsigned long long key[512];
  int b = blockIdx.x, tid = threadIdx.x;
  for (int i=tid;i<512;i+=256) {
    int gi = b*512 + i;
    key[i] = (gi < M_CELLS) ? packkey(cs[gi], gi) : 0ULL;
  }
  __syncthreads();
  for (int size=2; size<=512; size<<=1) {
    for (int st=size>>1; st>0; st>>=1) {
      for (int i=tid;i<512;i+=256) {
        int pp = i ^ st;
        if (pp > i) {
          unsigned long long a=key[i], bb=key[pp];
          bool desc = (((b*512+i) & size) == 0);
          if (desc ? (a<bb) : (a>bb)) { key[i]=bb; key[pp]=a; }
        }
      }
      __syncthreads();
    }
  }
  for (int i=tid;i<512;i+=256) keys[b*512+i] = key[i];
}

// ===================== K3b: bitonic sizes 1024..4096 merge + emit top500 =====================
__global__ __launch_bounds__(1024) void k3b_merge(const unsigned long long* __restrict__ keys,
    const float* __restrict__ summ,
    int* __restrict__ tidx, float* __restrict__ tsc, float* __restrict__ smt) {
  __shared__ unsigned long long key[4096];
  int tid = threadIdx.x;
  for (int i=tid;i<4096;i+=1024) key[i] = keys[i];
  __syncthreads();
  for (int size=1024; size<=4096; size<<=1) {
    for (int st=size>>1; st>0; st>>=1) {
      for (int i=tid;i<4096;i+=1024) {
        int pp = i ^ st;
        if (pp > i) {
          unsigned long long a=key[i], b=key[pp];
          bool desc = ((i & size) == 0);
          if (desc ? (a<b) : (a>b)) { key[i]=b; key[pp]=a; }
        }
      }
      __syncthreads();
    }
  }
  if (tid < 512) {
    if (tid < 500) {
      unsigned long long k = key[tid];
      int idx = (int)(0xFFFFFFFFu - (unsigned)(k & 0xFFFFFFFFull));
      tidx[tid] = idx;
      tsc[tid] = __uint_as_float((unsigned)(k>>32));
      smt[tid] = summ[idx];
    } else { tidx[tid]=0; tsc[tid]=0.f; smt[tid]=0.f; }
  }
}

// ===================== K4: pairwise mask IoU via bitset AND+popcount =====================
__global__ __launch_bounds__(256) void k4_iou(
    const unsigned long long* __restrict__ bits, const int* __restrict__ tidx,
    const int* __restrict__ rmap, const float* __restrict__ smt, float* __restrict__ iou) {
  int ti = blockIdx.y, tj = blockIdx.x;
  int tid = threadIdx.x;
  int ty = tid>>4, tx = tid&15;
  int i = ti*16+ty, j = tj*16+tx;
  if (ti > tj) { if (i<500 && j<500) iou[i*500+j] = 0.f; return; }
  __shared__ unsigned long long A[16][130];
  __shared__ unsigned long long B[16][130];
  __shared__ float sa[16], sb[16];
  if (tid<16) sa[tid] = (ti*16+tid<500) ? smt[ti*16+tid] : 0.f;
  else if (tid<32) sb[tid-16] = (tj*16+tid-16<500) ? smt[tj*16+tid-16] : 0.f;
  int inter = 0;
  for (int half=0; half<2; half++) {
    __syncthreads();
    for (int t=tid;t<2048;t+=256) {
      int r=t>>7, k=t&127;
      int ii = ti*16+r;
      int jj = tj*16+r;
      int ri = (ii<500) ? (rmap ? max(rmap[tidx[ii]],0) : tidx[ii]) : 0;
      int rj = (jj<500) ? (rmap ? max(rmap[tidx[jj]],0) : tidx[jj]) : 0;
      A[r][k] = (ii<500) ? bits[(size_t)ri*256 + half*128 + k] : 0ULL;
      B[r][k] = (jj<500) ? bits[(size_t)rj*256 + half*128 + k] : 0ULL;
    }
    __syncthreads();
    for (int k=0;k<128;k++) inter += __popcll(A[ty][k] & B[tx][k]);
  }
  if (i<500 && j<500) {
    float fi = (float)inter;
    float un = sa[ty] + sb[tx] - fi;
    iou[i*500+j] = (i<j) ? fi / fmaxf(un, 1.f) : 0.f;
  }
}

// ===================== K5: comp[j] = max_i iou[i][j] — parallel + ILP =====================
__global__ __launch_bounds__(256) void k5_comp(const float* __restrict__ iou, float* __restrict__ comp) {
  int tid = threadIdx.x;
  int tx = tid & 63, ty = tid >> 6;
  int j = blockIdx.x*64 + tx;
  float m0=0.f, m1=0.f, m2=0.f, m3=0.f;
  if (j < 500) {
    int i = ty;
    for (; i+12 < 500; i += 16) {
      m0 = fmaxf(m0, iou[(i   )*500 + j]);
      m1 = fmaxf(m1, iou[(i+ 4)*500 + j]);
      m2 = fmaxf(m2, iou[(i+ 8)*500 + j]);
      m3 = fmaxf(m3, iou[(i+12)*500 + j]);
    }
    for (; i < 500; i += 4) m0 = fmaxf(m0, iou[i*500 + j]);
  }
  float m = fmaxf(fmaxf(m0,m1), fmaxf(m2,m3));
  __shared__ float red[4][64];
  red[ty][tx] = m;
  __syncthreads();
  if (ty == 0 && j < 512)
    comp[j] = (j < 500) ? fmaxf(fmaxf(red[0][tx],red[1][tx]), fmaxf(red[2][tx],red[3][tx])) : 0.f;
}

// ===================== K6: decay + threshold — parallel + ILP =====================
__global__ __launch_bounds__(256) void k6_decay(
    const float* __restrict__ iou, const float* __restrict__ comp,
    const float* __restrict__ tsc, float* __restrict__ nms) {
  __shared__ float csh[512];
  int tid = threadIdx.x;
  for (int i=tid; i<512; i+=256) csh[i] = (i<500) ? comp[i] : 0.f;
  __syncthreads();
  int tx = tid & 63, ty = tid >> 6;
  int j = blockIdx.x*64 + tx;
  float t0=-1e30f, t1=-1e30f, t2=-1e30f, t3=-1e30f;
  if (j < 500) {
    int i = ty;
    for (; i+12 < 500; i += 16) {
      float v0 = iou[(i   )*500 + j], c0 = csh[i];
      float v1 = iou[(i+ 4)*500 + j], c1 = csh[i+4];
      float v2 = iou[(i+ 8)*500 + j], c2 = csh[i+8];
      float v3 = iou[(i+12)*500 + j], c3 = csh[i+12];
      t0 = fmaxf(t0, v0*v0 - c0*c0);
      t1 = fmaxf(t1, v1*v1 - c1*c1);
      t2 = fmaxf(t2, v2*v2 - c2*c2);
      t3 = fmaxf(t3, v3*v3 - c3*c3);
    }
    for (; i < 500; i += 4) { float v = iou[i*500 + j]; float c = csh[i]; t0 = fmaxf(t0, v*v - c*c); }
  }
  float t = fmaxf(fmaxf(t0,t1), fmaxf(t2,t3));
  __shared__ float red[4][64];
  red[ty][tx] = t;
  __syncthreads();
  if (ty == 0 && j < 512) {
    float out = 0.f;
    if (j < 500) {
      float tt = fmaxf(fmaxf(red[0][tx],red[1][tx]), fmaxf(red[2][tx],red[3][tx]));
      float s = tsc[j] * __expf(-2.f*tt);
      out = (s >= 0.05f) ? s : 0.f;
    }
    nms[j] = out;
  }
}

// ===================== K7: top-30 (+ fused Af30 pack when kfT != null) =====================
__global__ __launch_bounds__(256) void k7_top30(
    const float* __restrict__ nms, const int* __restrict__ tidx,
    int* __restrict__ sel, float* __restrict__ out,
    const float* __restrict__ kfT, _Float16* __restrict__ Af30) {
  __shared__ unsigned long long key[512];
  __shared__ int selsh[30];
  int tid = threadIdx.x;
  for (int i=tid;i<512;i+=256) key[i] = (i<500) ? packkey(nms[i], i) : 0ULL;
  __syncthreads();
  for (int size=2; size<=512; size<<=1) {
    for (int st=size>>1; st>0; st>>=1) {
      for (int i=tid;i<512;i+=256) {
        int pp = i ^ st;
        if (pp > i) {
          unsigned long long a=key[i], b=key[pp];
          bool desc = ((i & size) == 0);
          if (desc ? (a<b) : (a>b)) { key[i]=b; key[pp]=a; }
        }
      }
      __syncthreads();
    }
  }
  if (tid < 30) {
    unsigned long long k = key[tid];
    int j = (int)(0xFFFFFFFFu - (unsigned)(k & 0xFFFFFFFFull));
    float v = __uint_as_float((unsigned)(k>>32));
    out[120+tid] = v;
    out[150+tid] = (v > 0.3f) ? 1.f : 0.f;
    sel[tid] = tidx[j];
    selsh[tid] = tidx[j];
  }
  __syncthreads();
  if (kfT) {
    for (int P = tid; P < 1024; P += 256) {
      int sub = P >> 7, pc = P & 127;
      int ks = sub >> 1, h = sub & 1;
      int mn = pc >> 6, ln = pc & 63;
      int m  = mn*16 + (ln & 15);
      int kb = ks*32 + (ln >> 4)*8;
      half8 o;
      if (m < 30) {
        const float* src = kfT + selsh[m];
        #pragma unroll
        for (int j=0;j<8;j++) {
          float x = src[(size_t)(kb+j)*M_PAD];
          _Float16 hi = (_Float16)x;
          o[j] = h ? (_Float16)(x - (float)hi) : hi;
        }
      } else {
        #pragma unroll
        for (int j=0;j<8;j++) o[j] = (_Float16)0.f;
      }
      *(half8*)&Af30[(size_t)P*8] = o;
    }
  }
}

// ===================== K8 (MFMA): 32x16384x128 GEMM -> selp probs =====================
__global__ __launch_bounds__(256) void k8_mfma(const _Float16* __restrict__ Af30,
                                               const _Float16* __restrict__ Bf,
                                               float* __restrict__ selp) {
  const int nb = blockIdx.x;
  const int lane = threadIdx.x & 63;
  const int w = threadIdx.x >> 6;
  const half8* A = (const half8*)Af30;                    // [sub][128]
  const half8* B = (const half8*)Bf + (size_t)nb*4096;    // [sub][512]
  f32x4 acc[2][2];
  #pragma unroll
  for (int a=0;a<2;a++)
    #pragma unroll
    for (int b=0;b<2;b++) acc[a][b] = (f32x4){0.f,0.f,0.f,0.f};
  #pragma unroll
  for (int ks=0; ks<4; ks++) {
    half8 ah[2], bh[2], al[2], bl[2];
    #pragma unroll
    for (int mt=0; mt<2; mt++) ah[mt] = A[(ks*2+0)*128 + mt*64 + lane];
    #pragma unroll
    for (int nt=0; nt<2; nt++) bh[nt] = B[(size_t)(ks*2+0)*512 + (w*2+nt)*64 + lane];
    #pragma unroll
    for (int mt=0; mt<2; mt++) al[mt] = A[(ks*2+1)*128 + mt*64 + lane];
    #pragma unroll
    for (int nt=0; nt<2; nt++) bl[nt] = B[(size_t)(ks*2+1)*512 + (w*2+nt)*64 + lane];
    #pragma unroll
    for (int nt=0; nt<2; nt++)
      #pragma unroll
      for (int mt=0; mt<2; mt++) {
        acc[mt][nt] = __builtin_amdgcn_mfma_f32_16x16x32_f16(ah[mt], bh[nt], acc[mt][nt], 0, 0, 0);
        acc[mt][nt] = __builtin_amdgcn_mfma_f32_16x16x32_f16(ah[mt], bl[nt], acc[mt][nt], 0, 0, 0);
        acc[mt][nt] = __builtin_amdgcn_mfma_f32_16x16x32_f16(al[mt], bh[nt], acc[mt][nt], 0, 0, 0);
      }
  }
  const int q = lane >> 4, col = lane & 15;
  #pragma unroll
  for (int mt=0; mt<2; mt++)
    #pragma unroll
    for (int nt=0; nt<2; nt++)
      #pragma unroll
      for (int reg=0; reg<4; reg++) {
        int m = mt*16 + q*4 + reg;
        if (m < 30) {
          int px = nb*128 + w*32 + nt*16 + col;
          float lg = acc[mt][nt][reg];
          selp[(size_t)m*NPIX + px] = __fdividef(1.f, 1.f + __expf(-lg));
        }
      }
}

// ===================== K8 (fallback): probs for 30 selected masks =====================
__global__ __launch_bounds__(256) void k8_selp(
    const float* __restrict__ kf, const float* __restrict__ seg,
    const int* __restrict__ sel, float* __restrict__ selp) {
  int px = blockIdx.x*256 + threadIdx.x;
  int cells[30];
  #pragma unroll
  for (int m=0;m<30;m++) cells[m] = __builtin_amdgcn_readfirstlane(sel[m]);
  float acc[30];
  #pragma unroll
  for (int m=0;m<30;m++) acc[m] = 0.f;
  for (int e=0; e<128; e+=4) {
    float s0 = seg[(size_t)(e+0)*NPIX + px];
    float s1 = seg[(size_t)(e+1)*NPIX + px];
    float s2 = seg[(size_t)(e+2)*NPIX + px];
    float s3 = seg[(size_t)(e+3)*NPIX + px];
    #pragma unroll
    for (int m=0;m<30;m++) {
      const float* kr = kf + (size_t)cells[m]*128 + e;
      acc[m] = fmaf(kr[0], s0, fmaf(kr[1], s1, fmaf(kr[2], s2, fmaf(kr[3], s3, acc[m]))));
    }
  }
  #pragma unroll
  for (int m=0;m<30;m++)
    selp[(size_t)m*NPIX + px] = __fdividef(1.f, 1.f + __expf(-acc[m]));
}

// ===================== K9a: per-(mask,row) upsample -> per-row min/max =====================
__global__ __launch_bounds__(256) void k9a_rows(const float* __restrict__ selp,
                                               int* __restrict__ rowmn, int* __restrict__ rowmx) {
  int msk = blockIdx.y, oy = blockIdx.x;
  const float* mp = selp + (size_t)msk*NPIX;
  __shared__ float rows[2][128];
  __shared__ int wmn[4], wmx[4];
  int tid = threadIdx.x;
  float yf = fminf(fmaxf((oy+0.5f)*0.25f - 0.5f, 0.f), 127.f);
  int y0 = (int)yf, y1 = min(y0+1,127);
  float fy = yf-(float)y0;
  if (tid < 128) rows[0][tid] = mp[y0*128 + tid];
  else           rows[1][tid-128] = mp[y1*128 + tid-128];
  __syncthreads();
  int mnx = 512, mxx = -1;
  #pragma unroll
  for (int h=0; h<2; h++) {
    int ox = tid + h*256;
    float xf = fminf(fmaxf((ox+0.5f)*0.25f - 0.5f, 0.f), 127.f);
    int x0 = (int)xf, x1 = min(x0+1,127);
    float fx = xf-(float)x0;
    float v0 = rows[0][x0]*(1.f-fx) + rows[0][x1]*fx;
    float v1 = rows[1][x0]*(1.f-fx) + rows[1][x1]*fx;
    float v  = v0*(1.f-fy) + v1*fy;
    if (v > 0.5f) { mnx = min(mnx, ox); mxx = max(mxx, ox); }
  }
  #pragma unroll
  for (int o=32;o>0;o>>=1) {
    mnx = min(mnx, __shfl_down(mnx, o));
    mxx = max(mxx, __shfl_down(mxx, o));
  }
  if ((tid & 63) == 0) { wmn[tid>>6] = mnx; wmx[tid>>6] = mxx; }
  __syncthreads();
  if (tid == 0) {
    rowmn[msk*512 + oy] = min(min(wmn[0],wmn[1]), min(wmn[2],wmn[3]));
    rowmx[msk*512 + oy] = max(max(wmx[0],wmx[1]), max(wmx[2],wmx[3]));
  }
}

// ===================== K9b: per-row results -> bbox (LDS tree reduce) =====================
__global__ __launch_bounds__(512) void k9b_box(const int* __restrict__ rowmn,
                                              const int* __restrict__ rowmx, float* out) {
  int msk = blockIdx.x, tid = threadIdx.x;
  __shared__ int r0[512], r1[512], r2[512], r3[512];
  int mn = rowmn[msk*512 + tid];
  int mx = rowmx[msk*512 + tid];
  bool occ = (mx >= 0);
  r0[tid] = mn;
  r1[tid] = mx;
  r2[tid] = occ ? tid : 512;
  r3[tid] = occ ? tid : -1;
  __syncthreads();
  for (int s=256;s>0;s>>=1) {
    if (tid<s) {
      r0[tid]=min(r0[tid],r0[tid+s]); r1[tid]=max(r1[tid],r1[tid+s]);
      r2[tid]=min(r2[tid],r2[tid+s]); r3[tid]=max(r3[tid],r3[tid+s]);
    }
    __syncthreads();
  }
  if (tid==0) {
    bool vis = out[120+msk] > 0.3f;
    out[msk*4+0] = vis ? (float)r0[0] : 0.f;   // xmin (512 if empty, matches ref)
    out[msk*4+1] = vis ? (float)r2[0] : 0.f;   // ymin
    out[msk*4+2] = vis ? (float)r1[0] : 0.f;   // xmax (-1 if empty)
    out[msk*4+3] = vis ? (float)r3[0] : 0.f;   // ymax
  }
}

// ===================== launch =====================
extern "C" void kernel_launch(void* const* d_in, const int* in_sizes, int n_in,
                              void* d_out, int out_size, void* d_ws, size_t ws_size,
                              hipStream_t stream) {
  (void)in_sizes; (void)n_in; (void)out_size;
  if (ws_size < WS_FB) return;
  const float* cate[5]; const float* kern[5];
  for (int i=0;i<5;i++){ cate[i]=(const float*)d_in[2*i]; kern[i]=(const float*)d_in[2*i+1]; }
  const float* seg = (const float*)d_in[10];
  char* ws = (char*)d_ws;
  float* out = (float*)d_out;

  const bool mfma = (ws_size >= WS_MFMA);

  float* kf      = (float*)(ws + (mfma ? B_KF   : F_KF));   // MFMA path: kfT e-major
  float* scores  = (float*)(ws + (mfma ? B_SC   : F_SC));
  float* summ    = (float*)(ws + (mfma ? B_SM   : F_SM));
  float* cs      = (float*)(ws + (mfma ? B_CS   : F_CS));
  unsigned long long* bits = (unsigned long long*)(ws + (mfma ? B_BIT : F_BIT));
  float* spp     = (float*)(ws + (mfma ? B_SPP  : F_SPP));
  int*   tidx    = (int*)(ws + (mfma ? B_TIDX : F_TIDX));
  float* tsc     = (float*)(ws + (mfma ? B_TSC  : F_TSC));
  float* smt     = (float*)(ws + (mfma ? B_SMT  : F_SMT));
  float* iou     = (float*)(ws + (mfma ? B_IOU  : F_IOU));
  float* comp    = (float*)(ws + (mfma ? B_COMP : F_COMP));
  float* nms     = (float*)(ws + (mfma ? B_NMS  : F_NMS));
  int*   sel     = (int*)(ws + (mfma ? B_SEL  : F_SEL));
  float* selp    = (float*)(ws + (mfma ? B_SELP : F_SELP));
  int*   rowmn   = (int*)(ws + (mfma ? B_RMN  : F_RMN));
  int*   rowmx   = (int*)(ws + (mfma ? B_RMX  : F_RMX));
  unsigned long long* keys = (unsigned long long*)(ws + (mfma ? B_KEYS : F_KEYS));

  if (mfma) {
    _Float16* Af = (_Float16*)(ws + B_AFR);
    _Float16* Bf = (_Float16*)(ws + B_BFR);
    _Float16* Af30 = (_Float16*)(ws + B_AF30);
    int* cmap = (int*)(ws + B_CMAP);
    int* rmap = (int*)(ws + B_RMAP);
    int* vcnt = (int*)(ws + B_VCNT);
    hipMemsetAsync(vcnt, 0, 4, stream);
    k0aT_gather<<<dim3(800,5), 256, 0, stream>>>(cate[0],cate[1],cate[2],cate[3],cate[4],
                                      kern[0],kern[1],kern[2],kern[3],kern[4],
                                      kf, scores, cmap, rmap, vcnt);
    k0c_bfrag<<<128*4096/256, 256, 0, stream>>>(seg, Bf);
    k0b_afrag<<<31*4096/256, 256, 0, stream>>>(kf, cmap, vcnt, Af);
    k1_mfma  <<<dim3(31, 128), 256, 0, stream>>>(Af, Bf, vcnt, bits, spp);
    k2c_cscore<<<M_CELLS/4, 256, 0, stream>>>(bits, spp, scores, rmap, summ, cs);
    k3a_sort512<<<8, 256, 0, stream>>>(cs, keys);
    k3b_merge  <<<1, 1024, 0, stream>>>(keys, summ, tidx, tsc, smt);
    k4_iou   <<<dim3(32,32), 256, 0, stream>>>(bits, tidx, rmap, smt, iou);
    k5_comp  <<<8, 256, 0, stream>>>(iou, comp);
    k6_decay <<<8, 256, 0, stream>>>(iou, comp, tsc, nms);
    k7_top30 <<<1, 256, 0, stream>>>(nms, tidx, sel, out, kf, Af30);
    k8_mfma  <<<128, 256, 0, stream>>>(Af30, Bf, selp);
  } else {
    k0a_gather<<<dim3(800,5), 256, 0, stream>>>(cate[0],cate[1],cate[2],cate[3],cate[4],
                                      kern[0],kern[1],kern[2],kern[3],kern[4], kf, scores);
    k1_gemm  <<<dim3(64,121), 256, 0, stream>>>(kf, seg, bits, spp);
    k2_cscore<<<M_CELLS/4, 256, 0, stream>>>(bits, spp, scores, summ, cs, 64, M_CELLS);
    k3a_sort512<<<8, 256, 0, stream>>>(cs, keys);
    k3b_merge  <<<1, 1024, 0, stream>>>(keys, summ, tidx, tsc, smt);
    k4_iou   <<<dim3(32,32), 256, 0, stream>>>(bits, tidx, nullptr, smt, iou);
    k5_comp  <<<8, 256, 0, stream>>>(iou, comp);
    k6_decay <<<8, 256, 0, stream>>>(iou, comp, tsc, nms);
    k7_top30 <<<1, 256, 0, stream>>>(nms, tidx, sel, out, nullptr, nullptr);
    k8_selp  <<<NPIX/256, 256, 0, stream>>>(kf, seg, sel, selp);
  }
  k9a_rows <<<dim3(512,30), 256, 0, stream>>>(selp, rowmn, rowmx);
  k9b_box  <<<30, 512, 0, stream>>>(rowmn, rowmx, out);
}